// Round 4
// baseline (6706.246 us; speedup 1.0000x reference)
//
#include <hip/hip_runtime.h>
#include <hip/hip_bf16.h>

typedef __hip_bfloat16 bf16;

#define D_MODEL 1024
#define D_STATE 16
#define D_INNER 2048
#define DT_RANK 64
#define BB 2
#define LL 2048
#define BL (BB * LL)            // 4096 rows
#define XZ_LD (2 * D_INNER)     // 4096
#define DBL_LD (DT_RANK + 2 * D_STATE)  // 96

// ---------------- LayerNorm: one block per row ----------------
__global__ __launch_bounds__(256) void ln_kernel(
    const float* __restrict__ x, const float* __restrict__ w,
    const float* __restrict__ b, float* __restrict__ xn)
{
    __shared__ float s1[256], s2[256];
    const int row = blockIdx.x;
    const int tid = threadIdx.x;
    const float* xr = x + (size_t)row * D_MODEL;
    float v[4], sum = 0.f, sq = 0.f;
#pragma unroll
    for (int i = 0; i < 4; ++i) {
        v[i] = xr[tid + 256 * i];
        sum += v[i];
        sq  += v[i] * v[i];
    }
    s1[tid] = sum; s2[tid] = sq;
    __syncthreads();
    for (int s = 128; s > 0; s >>= 1) {
        if (tid < s) { s1[tid] += s1[tid + s]; s2[tid] += s2[tid + s]; }
        __syncthreads();
    }
    const float mu  = s1[0] * (1.f / D_MODEL);
    const float var = s2[0] * (1.f / D_MODEL) - mu * mu;
    const float rs  = rsqrtf(var + 1e-5f);
#pragma unroll
    for (int i = 0; i < 4; ++i) {
        const int c = tid + 256 * i;
        xn[(size_t)row * D_MODEL + c] =
            (v[i] - mu) * rs * w[c] + b[c];
    }
}

// ---------------- Generic GEMM: C[M,N] = A[M,K](fp32,lda) * Bw[N,K](fp32)^T ---
// epi: 0 = raw fp32 store; 1 = +bias then softplus; 2 = +resid, fp32 store
#define BM 128
#define BN 128
#define BK 8

__global__ __launch_bounds__(256) void gemm_bt(
    const float* __restrict__ A, int lda,
    const float* __restrict__ Bw,
    float* __restrict__ C, int ldc,
    int M, int N, int K, int epi,
    const float* __restrict__ bias,
    const float* __restrict__ resid)
{
    __shared__ float As[BK][BM + 1];
    __shared__ float Bs[BK][BN + 1];
    const int tx = threadIdx.x, ty = threadIdx.y;
    const int tid = ty * 16 + tx;
    const int bm = blockIdx.y * BM, bn = blockIdx.x * BN;

    float acc[8][8];
#pragma unroll
    for (int i = 0; i < 8; ++i)
#pragma unroll
        for (int j = 0; j < 8; ++j) acc[i][j] = 0.f;

    for (int k0 = 0; k0 < K; k0 += BK) {
        // M % BM == 0 and K % BK == 0 for all call sites; only N can be ragged
#pragma unroll
        for (int i = tid; i < BM * BK; i += 256) {
            const int m = i / BK, kk = i % BK;
            As[kk][m] = A[(size_t)(bm + m) * lda + (k0 + kk)];
        }
#pragma unroll
        for (int i = tid; i < BN * BK; i += 256) {
            const int n = i / BK, kk = i % BK;
            const int gn = bn + n;
            Bs[kk][n] = (gn < N) ? Bw[(size_t)gn * K + (k0 + kk)] : 0.f;
        }
        __syncthreads();
#pragma unroll
        for (int kk = 0; kk < BK; ++kk) {
            float av[8], bv[8];
#pragma unroll
            for (int i = 0; i < 8; ++i) av[i] = As[kk][ty * 8 + i];
#pragma unroll
            for (int j = 0; j < 8; ++j) bv[j] = Bs[kk][tx * 8 + j];
#pragma unroll
            for (int i = 0; i < 8; ++i)
#pragma unroll
                for (int j = 0; j < 8; ++j) acc[i][j] += av[i] * bv[j];
        }
        __syncthreads();
    }

#pragma unroll
    for (int i = 0; i < 8; ++i) {
        const int gm = bm + ty * 8 + i;
#pragma unroll
        for (int j = 0; j < 8; ++j) {
            const int gn = bn + tx * 8 + j;
            if (gn >= N) continue;
            float v = acc[i][j];
            if (epi == 1) {
                v += bias[gn];
                // numerically-stable softplus
                v = fmaxf(v, 0.f) + log1pf(expf(-fabsf(v)));
            } else if (epi == 2) {
                v += resid[(size_t)gm * ldc + gn];
            }
            C[(size_t)gm * ldc + gn] = v;
        }
    }
}

// ---------------- depthwise causal conv(4) + SiLU, in-place on u half of xz ---
// exactly BB*D_INNER = 4096 threads -> grid 16 x 256
__global__ __launch_bounds__(256) void conv_silu_kernel(
    float* __restrict__ xz, const float* __restrict__ cw,
    const float* __restrict__ cb)
{
    const int idx = blockIdx.x * 256 + threadIdx.x;  // 0..4095
    const int b = idx >> 11, d = idx & (D_INNER - 1);
    const float w0 = cw[d * 4 + 0], w1 = cw[d * 4 + 1];
    const float w2 = cw[d * 4 + 2], w3 = cw[d * 4 + 3];
    const float bias = cb[d];
    float* u = xz + (size_t)b * LL * XZ_LD + d;
    float x0 = 0.f, x1 = 0.f, x2 = 0.f;
    for (int t = 0; t < LL; ++t) {
        const float x3 = u[(size_t)t * XZ_LD];
        const float c = bias + x0 * w0 + x1 * w1 + x2 * w2 + x3 * w3;
        u[(size_t)t * XZ_LD] = c / (1.f + expf(-c));  // SiLU
        x0 = x1; x1 = x2; x2 = x3;
    }
}

// ---------------- selective scan, thread per (b,d); y overwrites u in-place ---
__global__ __launch_bounds__(256) void scan_kernel(
    float* __restrict__ xz,          // u at col 0, z at col 2048, stride 4096
    const float* __restrict__ dtb,   // [BL, 2048]
    const float* __restrict__ dbl,   // [BL, 96]
    const float* __restrict__ A_log, const float* __restrict__ Dw)
{
    const int idx = blockIdx.x * 256 + threadIdx.x;  // 0..4095
    const int b = idx >> 11, d = idx & (D_INNER - 1);
    float A[D_STATE], h[D_STATE];
#pragma unroll
    for (int n = 0; n < D_STATE; ++n) {
        A[n] = -expf(A_log[d * D_STATE + n]);
        h[n] = 0.f;
    }
    const float Dd = Dw[d];
    const float* dtp  = dtb + (size_t)b * LL * D_INNER + d;
    float*       up   = xz  + (size_t)b * LL * XZ_LD + d;
    const float* dblp = dbl + (size_t)b * LL * DBL_LD;

    for (int t = 0; t < LL; ++t) {
        const float dtv = dtp[(size_t)t * D_INNER];
        const float uv  = up[(size_t)t * XZ_LD];
        const float zv  = up[(size_t)t * XZ_LD + D_INNER];
        const float* Brow = dblp + (size_t)t * DBL_LD + DT_RANK;       // B: 16
        const float* Crow = Brow + D_STATE;                            // C: 16
        const float du = dtv * uv;
        float acc = uv * Dd;
#pragma unroll
        for (int n = 0; n < D_STATE; ++n) {
            const float dA = expf(dtv * A[n]);
            h[n] = dA * h[n] + du * Brow[n];
            acc += h[n] * Crow[n];
        }
        const float sz = zv / (1.f + expf(-zv));  // silu(z)
        up[(size_t)t * XZ_LD] = acc * sz;         // y in place of u
    }
}

extern "C" void kernel_launch(void* const* d_in, const int* in_sizes, int n_in,
                              void* d_out, int out_size, void* d_ws, size_t ws_size,
                              hipStream_t stream)
{
    // Reference inputs are float32 -> const float*; reference OUTPUT is
    // float32 -> d_out is float* (harness doc). R3's bf16 store packed two
    // halves per fp32 word -> err 7.06; this round stores fp32.
    const float* x       = (const float*)d_in[0];
    const float* ln_w    = (const float*)d_in[1];
    const float* ln_b    = (const float*)d_in[2];
    const float* W_in    = (const float*)d_in[3];
    const float* conv_w  = (const float*)d_in[4];
    const float* conv_b  = (const float*)d_in[5];
    const float* W_xproj = (const float*)d_in[6];
    const float* W_dt    = (const float*)d_in[7];
    const float* b_dt    = (const float*)d_in[8];
    const float* A_log   = (const float*)d_in[9];
    const float* Dw      = (const float*)d_in[10];
    const float* W_out   = (const float*)d_in[11];
    float* out = (float*)d_out;

    // ws layout (fp32), with xn/dt overlapped (xn dead after GEMM-2, dt born at
    // GEMM-5):   [dtb: 4096*2048 | xz: 4096*4096 | dbl: 4096*96]
    // xn aliases the first 4096*1024 of dtb.   total = 97.5 MiB
    float* dtb = (float*)d_ws;
    float* xn  = dtb;                               // alias (disjoint lifetime)
    float* xz  = dtb + (size_t)BL * D_INNER;
    float* dbl = xz  + (size_t)BL * XZ_LD;

    // 1. LayerNorm
    ln_kernel<<<BL, 256, 0, stream>>>(x, ln_w, ln_b, xn);

    dim3 blk(16, 16);
    // 2. xz = xn @ W_in^T   (M=4096, N=4096, K=1024)
    gemm_bt<<<dim3(XZ_LD / BN, BL / BM), blk, 0, stream>>>(
        xn, D_MODEL, W_in, xz, XZ_LD, BL, XZ_LD, D_MODEL, 0, nullptr, nullptr);

    // 3. causal conv + SiLU on u (in place) — exactly BB*D_INNER threads
    conv_silu_kernel<<<(BB * D_INNER) / 256, 256, 0, stream>>>(xz, conv_w, conv_b);

    // 4. dbl = u @ W_xproj^T  (M=4096, N=96, K=2048)
    gemm_bt<<<dim3(1, BL / BM), blk, 0, stream>>>(
        xz, XZ_LD, W_xproj, dbl, DBL_LD, BL, DBL_LD, D_INNER, 0, nullptr, nullptr);

    // 5. dt = softplus(dt_r @ W_dt^T + b_dt)  (M=4096, N=2048, K=64)
    gemm_bt<<<dim3(D_INNER / BN, BL / BM), blk, 0, stream>>>(
        dbl, DBL_LD, W_dt, dtb, D_INNER, BL, D_INNER, DT_RANK, 1, b_dt, nullptr);

    // 6. selective scan (+ u*D, * silu(z)); y overwrites u
    scan_kernel<<<(BB * D_INNER) / 256, 256, 0, stream>>>(xz, dtb, dbl, A_log, Dw);

    // 7. out = y @ W_out^T + x  (M=4096, N=1024, K=2048), fp32 store
    gemm_bt<<<dim3(D_MODEL / BN, BL / BM), blk, 0, stream>>>(
        xz, XZ_LD, W_out, out, D_MODEL, BL, D_MODEL, D_INNER, 2, nullptr, x);
}

// Round 5
// 2402.628 us; speedup vs baseline: 2.7912x; 2.7912x over previous
//
#include <hip/hip_runtime.h>
#include <hip/hip_bf16.h>

typedef __hip_bfloat16 bf16;

#define D_MODEL 1024
#define D_STATE 16
#define D_INNER 2048
#define DT_RANK 64
#define BB 2
#define LL 2048
#define BL (BB * LL)            // 4096 rows
#define XZ_LD (2 * D_INNER)     // 4096
#define DBL_LD (DT_RANK + 2 * D_STATE)  // 96
#define NCH 32                  // time chunks for parallel scan
#define TCH (LL / NCH)          // 64 steps per chunk

// ---------------- LayerNorm: one block per row ----------------
__global__ __launch_bounds__(256) void ln_kernel(
    const float* __restrict__ x, const float* __restrict__ w,
    const float* __restrict__ b, float* __restrict__ xn)
{
    __shared__ float s1[256], s2[256];
    const int row = blockIdx.x;
    const int tid = threadIdx.x;
    const float* xr = x + (size_t)row * D_MODEL;
    float v[4], sum = 0.f, sq = 0.f;
#pragma unroll
    for (int i = 0; i < 4; ++i) {
        v[i] = xr[tid + 256 * i];
        sum += v[i];
        sq  += v[i] * v[i];
    }
    s1[tid] = sum; s2[tid] = sq;
    __syncthreads();
    for (int s = 128; s > 0; s >>= 1) {
        if (tid < s) { s1[tid] += s1[tid + s]; s2[tid] += s2[tid + s]; }
        __syncthreads();
    }
    const float mu  = s1[0] * (1.f / D_MODEL);
    const float var = s2[0] * (1.f / D_MODEL) - mu * mu;
    const float rs  = rsqrtf(var + 1e-5f);
#pragma unroll
    for (int i = 0; i < 4; ++i) {
        const int c = tid + 256 * i;
        xn[(size_t)row * D_MODEL + c] = (v[i] - mu) * rs * w[c] + b[c];
    }
}

// ---------------- Generic GEMM: C[M,N] = A[M,K](fp32,lda) * Bw[N,K](fp32)^T ---
// epi: 0 = raw fp32 store; 1 = +bias then softplus; 2 = +resid, fp32 store
#define BM 128
#define BN 128
#define BK 8

__global__ __launch_bounds__(256) void gemm_bt(
    const float* __restrict__ A, int lda,
    const float* __restrict__ Bw,
    float* __restrict__ C, int ldc,
    int M, int N, int K, int epi,
    const float* __restrict__ bias,
    const float* __restrict__ resid)
{
    __shared__ float As[BK][BM + 1];
    __shared__ float Bs[BK][BN + 1];
    const int tx = threadIdx.x, ty = threadIdx.y;
    const int tid = ty * 16 + tx;
    const int bm = blockIdx.y * BM, bn = blockIdx.x * BN;

    float acc[8][8];
#pragma unroll
    for (int i = 0; i < 8; ++i)
#pragma unroll
        for (int j = 0; j < 8; ++j) acc[i][j] = 0.f;

    for (int k0 = 0; k0 < K; k0 += BK) {
#pragma unroll
        for (int i = tid; i < BM * BK; i += 256) {
            const int m = i / BK, kk = i % BK;
            As[kk][m] = A[(size_t)(bm + m) * lda + (k0 + kk)];
        }
#pragma unroll
        for (int i = tid; i < BN * BK; i += 256) {
            const int n = i / BK, kk = i % BK;
            const int gn = bn + n;
            Bs[kk][n] = (gn < N) ? Bw[(size_t)gn * K + (k0 + kk)] : 0.f;
        }
        __syncthreads();
#pragma unroll
        for (int kk = 0; kk < BK; ++kk) {
            float av[8], bv[8];
#pragma unroll
            for (int i = 0; i < 8; ++i) av[i] = As[kk][ty * 8 + i];
#pragma unroll
            for (int j = 0; j < 8; ++j) bv[j] = Bs[kk][tx * 8 + j];
#pragma unroll
            for (int i = 0; i < 8; ++i)
#pragma unroll
                for (int j = 0; j < 8; ++j) acc[i][j] += av[i] * bv[j];
        }
        __syncthreads();
    }

#pragma unroll
    for (int i = 0; i < 8; ++i) {
        const int gm = bm + ty * 8 + i;
#pragma unroll
        for (int j = 0; j < 8; ++j) {
            const int gn = bn + tx * 8 + j;
            if (gn >= N) continue;
            float v = acc[i][j];
            if (epi == 1) {
                v += bias[gn];
                v = fmaxf(v, 0.f) + log1pf(expf(-fabsf(v)));  // stable softplus
            } else if (epi == 2) {
                v += resid[(size_t)gm * ldc + gn];
            }
            C[(size_t)gm * ldc + gn] = v;
        }
    }
}

// ======================= parallel conv + 3-phase scan =========================

// conv+SiLU, one thread per (b,t,d) element; reads raw u from xz, writes uc.
__global__ __launch_bounds__(256) void conv_par_kernel(
    const float* __restrict__ xz, const float* __restrict__ cw,
    const float* __restrict__ cb, float* __restrict__ uc)
{
    const int id = blockIdx.x * 256 + threadIdx.x;   // 0 .. B*L*D_INNER-1
    const int d = id & (D_INNER - 1);
    const int t = (id >> 11) & (LL - 1);
    const int b = id >> 22;
    const float* up = xz + (size_t)b * LL * XZ_LD + d;
    float acc = cb[d];
#pragma unroll
    for (int k = 0; k < 4; ++k) {
        const int tt = t - 3 + k;
        if (tt >= 0) acc += up[(size_t)tt * XZ_LD] * cw[d * 4 + k];
    }
    uc[(size_t)(b * LL + t) * D_INNER + d] = acc / (1.f + expf(-acc));
}

// phase 1: per (b,d,chunk) compute chunk decay P[n]=exp(A[n]*sum dt) and local h
__global__ __launch_bounds__(256) void scan_p1(
    const float* __restrict__ uc, const float* __restrict__ dtb,
    const float* __restrict__ dbl, const float* __restrict__ A_log,
    float* __restrict__ Psum, float* __restrict__ Hloc)
{
    const int blk = blockIdx.x;
    const int d = (blk & 7) * 256 + threadIdx.x;
    const int c = (blk >> 3) & (NCH - 1);
    const int b = blk >> 8;
    float A[D_STATE], h[D_STATE];
#pragma unroll
    for (int n = 0; n < D_STATE; ++n) {
        A[n] = -expf(A_log[d * D_STATE + n]);
        h[n] = 0.f;
    }
    const size_t row0 = (size_t)b * LL + c * TCH;
    const float* dtp = dtb + row0 * D_INNER + d;
    const float* up  = uc  + row0 * D_INNER + d;
    const float* Bp  = dbl + row0 * DBL_LD + DT_RANK;
    float S = 0.f;
    for (int t = 0; t < TCH; ++t) {
        const float dtv = dtp[(size_t)t * D_INNER];
        const float uv  = up[(size_t)t * D_INNER];
        const float du  = dtv * uv;
        S += dtv;
#pragma unroll
        for (int n = 0; n < D_STATE; ++n)
            h[n] = expf(dtv * A[n]) * h[n] + du * Bp[(size_t)t * DBL_LD + n];
    }
    const size_t o = (((size_t)b * NCH + c) * D_INNER + d) * D_STATE;
#pragma unroll
    for (int n = 0; n < D_STATE; ++n) {
        Psum[o + n] = expf(S * A[n]);
        Hloc[o + n] = h[n];
    }
}

// phase 2: serial combine over chunks; Psum is overwritten with Hin (state
// entering each chunk). One thread per (b,d,n).
__global__ __launch_bounds__(256) void scan_p2(
    float* __restrict__ Psum, const float* __restrict__ Hloc)
{
    const int id = blockIdx.x * 256 + threadIdx.x;   // 0 .. B*D_INNER*16-1
    const int dn = id & (D_INNER * D_STATE - 1);
    const int b  = id >> 15;
    float h = 0.f;
    for (int c = 0; c < NCH; ++c) {
        const size_t o = ((size_t)(b * NCH + c) * D_INNER * D_STATE) + dn;
        const float P  = Psum[o];
        const float hl = Hloc[o];
        Psum[o] = h;          // Hin for chunk c
        h = P * h + hl;
    }
}

// phase 3: replay chunk with true incoming h; fuse +u*D and *silu(z);
// y overwrites the (dead) raw-u columns of xz so GEMM-7 reads xz unchanged.
__global__ __launch_bounds__(256) void scan_p3(
    float* __restrict__ xz, const float* __restrict__ uc,
    const float* __restrict__ dtb, const float* __restrict__ dbl,
    const float* __restrict__ A_log, const float* __restrict__ Dw,
    const float* __restrict__ Hin)
{
    const int blk = blockIdx.x;
    const int d = (blk & 7) * 256 + threadIdx.x;
    const int c = (blk >> 3) & (NCH - 1);
    const int b = blk >> 8;
    float A[D_STATE], h[D_STATE];
    const size_t o = (((size_t)b * NCH + c) * D_INNER + d) * D_STATE;
#pragma unroll
    for (int n = 0; n < D_STATE; ++n) {
        A[n] = -expf(A_log[d * D_STATE + n]);
        h[n] = Hin[o + n];
    }
    const float Dd = Dw[d];
    const size_t row0 = (size_t)b * LL + c * TCH;
    const float* dtp = dtb + row0 * D_INNER + d;
    const float* up  = uc  + row0 * D_INNER + d;
    const float* BCp = dbl + row0 * DBL_LD;
    float* xzp = xz + ((size_t)b * LL + c * TCH) * XZ_LD + d;
    for (int t = 0; t < TCH; ++t) {
        const float dtv = dtp[(size_t)t * D_INNER];
        const float uv  = up[(size_t)t * D_INNER];
        const float du  = dtv * uv;
        float acc = uv * Dd;
        const float* Brow = BCp + (size_t)t * DBL_LD + DT_RANK;
        const float* Crow = Brow + D_STATE;
#pragma unroll
        for (int n = 0; n < D_STATE; ++n) {
            const float dA = expf(dtv * A[n]);
            h[n] = dA * h[n] + du * Brow[n];
            acc += h[n] * Crow[n];
        }
        const float zv = xzp[(size_t)t * XZ_LD + D_INNER];
        const float sz = zv / (1.f + expf(-zv));
        xzp[(size_t)t * XZ_LD] = acc * sz;   // y in place of raw u
    }
}

// ---------------- fallback (sequential) conv + scan, if ws too small ---------
__global__ __launch_bounds__(256) void conv_silu_kernel(
    float* __restrict__ xz, const float* __restrict__ cw,
    const float* __restrict__ cb)
{
    const int idx = blockIdx.x * 256 + threadIdx.x;
    const int b = idx >> 11, d = idx & (D_INNER - 1);
    const float w0 = cw[d * 4 + 0], w1 = cw[d * 4 + 1];
    const float w2 = cw[d * 4 + 2], w3 = cw[d * 4 + 3];
    const float bias = cb[d];
    float* u = xz + (size_t)b * LL * XZ_LD + d;
    float x0 = 0.f, x1 = 0.f, x2 = 0.f;
    for (int t = 0; t < LL; ++t) {
        const float x3 = u[(size_t)t * XZ_LD];
        const float c = bias + x0 * w0 + x1 * w1 + x2 * w2 + x3 * w3;
        u[(size_t)t * XZ_LD] = c / (1.f + expf(-c));
        x0 = x1; x1 = x2; x2 = x3;
    }
}

__global__ __launch_bounds__(256) void scan_kernel(
    float* __restrict__ xz, const float* __restrict__ dtb,
    const float* __restrict__ dbl,
    const float* __restrict__ A_log, const float* __restrict__ Dw)
{
    const int idx = blockIdx.x * 256 + threadIdx.x;
    const int b = idx >> 11, d = idx & (D_INNER - 1);
    float A[D_STATE], h[D_STATE];
#pragma unroll
    for (int n = 0; n < D_STATE; ++n) {
        A[n] = -expf(A_log[d * D_STATE + n]);
        h[n] = 0.f;
    }
    const float Dd = Dw[d];
    const float* dtp  = dtb + (size_t)b * LL * D_INNER + d;
    float*       up   = xz  + (size_t)b * LL * XZ_LD + d;
    const float* dblp = dbl + (size_t)b * LL * DBL_LD;
    for (int t = 0; t < LL; ++t) {
        const float dtv = dtp[(size_t)t * D_INNER];
        const float uv  = up[(size_t)t * XZ_LD];
        const float zv  = up[(size_t)t * XZ_LD + D_INNER];
        const float* Brow = dblp + (size_t)t * DBL_LD + DT_RANK;
        const float* Crow = Brow + D_STATE;
        const float du = dtv * uv;
        float acc = uv * Dd;
#pragma unroll
        for (int n = 0; n < D_STATE; ++n) {
            const float dA = expf(dtv * A[n]);
            h[n] = dA * h[n] + du * Brow[n];
            acc += h[n] * Crow[n];
        }
        const float sz = zv / (1.f + expf(-zv));
        up[(size_t)t * XZ_LD] = acc * sz;
    }
}

extern "C" void kernel_launch(void* const* d_in, const int* in_sizes, int n_in,
                              void* d_out, int out_size, void* d_ws, size_t ws_size,
                              hipStream_t stream)
{
    const float* x       = (const float*)d_in[0];
    const float* ln_w    = (const float*)d_in[1];
    const float* ln_b    = (const float*)d_in[2];
    const float* W_in    = (const float*)d_in[3];
    const float* conv_w  = (const float*)d_in[4];
    const float* conv_b  = (const float*)d_in[5];
    const float* W_xproj = (const float*)d_in[6];
    const float* W_dt    = (const float*)d_in[7];
    const float* b_dt    = (const float*)d_in[8];
    const float* A_log   = (const float*)d_in[9];
    const float* Dw      = (const float*)d_in[10];
    const float* W_out   = (const float*)d_in[11];
    float* out = (float*)d_out;

    // ws layout (fp32):
    //   [dtb 8.39M | xz 16.78M | dbl 0.39M | uc 8.39M | Psum 2.10M | Hloc 2.10M]
    // xn aliases dtb (disjoint lifetimes). Fast path needs 145.5 MiB.
    float* dtb  = (float*)d_ws;
    float* xn   = dtb;
    float* xz   = dtb + (size_t)BL * D_INNER;
    float* dbl  = xz  + (size_t)BL * XZ_LD;
    float* uc   = dbl + (size_t)BL * DBL_LD;
    float* Psum = uc  + (size_t)BL * D_INNER;
    float* Hloc = Psum + (size_t)BB * NCH * D_INNER * D_STATE;
    const size_t need_floats =
        (size_t)BL * D_INNER + (size_t)BL * XZ_LD + (size_t)BL * DBL_LD +
        (size_t)BL * D_INNER + 2 * (size_t)BB * NCH * D_INNER * D_STATE;
    const bool fast = ws_size >= need_floats * sizeof(float);

    // 1. LayerNorm
    ln_kernel<<<BL, 256, 0, stream>>>(x, ln_w, ln_b, xn);

    dim3 blk(16, 16);
    // 2. xz = xn @ W_in^T   (M=4096, N=4096, K=1024)
    gemm_bt<<<dim3(XZ_LD / BN, BL / BM), blk, 0, stream>>>(
        xn, D_MODEL, W_in, xz, XZ_LD, BL, XZ_LD, D_MODEL, 0, nullptr, nullptr);

    if (fast) {
        // 3. parallel conv+SiLU: raw u (xz) -> uc
        conv_par_kernel<<<(size_t)BL * D_INNER / 256, 256, 0, stream>>>(
            xz, conv_w, conv_b, uc);
        // 4. dbl = uc @ W_xproj^T  (M=4096, N=96, K=2048)
        gemm_bt<<<dim3(1, BL / BM), blk, 0, stream>>>(
            uc, D_INNER, W_xproj, dbl, DBL_LD, BL, DBL_LD, D_INNER, 0, nullptr, nullptr);
        // 5. dt = softplus(dt_r @ W_dt^T + b_dt)
        gemm_bt<<<dim3(D_INNER / BN, BL / BM), blk, 0, stream>>>(
            dbl, DBL_LD, W_dt, dtb, D_INNER, BL, D_INNER, DT_RANK, 1, b_dt, nullptr);
        // 6. chunked parallel scan; y -> raw-u columns of xz
        scan_p1<<<BB * NCH * 8, 256, 0, stream>>>(uc, dtb, dbl, A_log, Psum, Hloc);
        scan_p2<<<BB * D_INNER * D_STATE / 256, 256, 0, stream>>>(Psum, Hloc);
        scan_p3<<<BB * NCH * 8, 256, 0, stream>>>(xz, uc, dtb, dbl, A_log, Dw, Psum);
    } else {
        conv_silu_kernel<<<(BB * D_INNER) / 256, 256, 0, stream>>>(xz, conv_w, conv_b);
        gemm_bt<<<dim3(1, BL / BM), blk, 0, stream>>>(
            xz, XZ_LD, W_xproj, dbl, DBL_LD, BL, DBL_LD, D_INNER, 0, nullptr, nullptr);
        gemm_bt<<<dim3(D_INNER / BN, BL / BM), blk, 0, stream>>>(
            dbl, DBL_LD, W_dt, dtb, D_INNER, BL, D_INNER, DT_RANK, 1, b_dt, nullptr);
        scan_kernel<<<(BB * D_INNER) / 256, 256, 0, stream>>>(xz, dtb, dbl, A_log, Dw);
    }

    // 7. out = y @ W_out^T + x  (M=4096, N=1024, K=2048), fp32 store
    gemm_bt<<<dim3(D_MODEL / BN, BL / BM), blk, 0, stream>>>(
        xz, XZ_LD, W_out, out, D_MODEL, BL, D_MODEL, D_INNER, 2, nullptr, x);
}

// Round 6
// 958.775 us; speedup vs baseline: 6.9946x; 2.5059x over previous
//
#include <hip/hip_runtime.h>
#include <hip/hip_bf16.h>

typedef __hip_bfloat16 bf16;
typedef __attribute__((ext_vector_type(8))) short short8;
typedef __attribute__((ext_vector_type(4))) float floatx4;

#define D_MODEL 1024
#define D_STATE 16
#define D_INNER 2048
#define DT_RANK 64
#define BB 2
#define LL 2048
#define BL (BB * LL)            // 4096 rows
#define XZ_LD (2 * D_INNER)     // 4096
#define DBL_LD (DT_RANK + 2 * D_STATE)  // 96
#define NCH 32                  // time chunks for parallel scan
#define TCH (LL / NCH)          // 64 steps per chunk

__device__ inline short f2bf(float f) {
    union { bf16 h; short s; } u;
    u.h = __float2bfloat16(f);
    return u.s;
}

// ---------------- LayerNorm: one block per row ----------------
__global__ __launch_bounds__(256) void ln_kernel(
    const float* __restrict__ x, const float* __restrict__ w,
    const float* __restrict__ b, float* __restrict__ xn)
{
    __shared__ float s1[256], s2[256];
    const int row = blockIdx.x;
    const int tid = threadIdx.x;
    const float* xr = x + (size_t)row * D_MODEL;
    float v[4], sum = 0.f, sq = 0.f;
#pragma unroll
    for (int i = 0; i < 4; ++i) {
        v[i] = xr[tid + 256 * i];
        sum += v[i];
        sq  += v[i] * v[i];
    }
    s1[tid] = sum; s2[tid] = sq;
    __syncthreads();
    for (int s = 128; s > 0; s >>= 1) {
        if (tid < s) { s1[tid] += s1[tid + s]; s2[tid] += s2[tid + s]; }
        __syncthreads();
    }
    const float mu  = s1[0] * (1.f / D_MODEL);
    const float var = s2[0] * (1.f / D_MODEL) - mu * mu;
    const float rs  = rsqrtf(var + 1e-5f);
#pragma unroll
    for (int i = 0; i < 4; ++i) {
        const int c = tid + 256 * i;
        xn[(size_t)row * D_MODEL + c] = (v[i] - mu) * rs * w[c] + b[c];
    }
}

// ============ MFMA bf16 GEMM: C[M,N] = A[M,K](fp32) * Bw[N,K](fp32)^T ========
// 128x128 tile, BK=32, 4 waves, each wave 4x4 tiles of 16x16x32 MFMA.
// fp32 -> bf16 conversion happens during LDS staging.
// epi: 0 = raw store; 1 = +bias softplus; 2 = +resid.
#define TM 128
#define TN 128
#define TK 32

__global__ __launch_bounds__(256) void gemm_mfma(
    const float* __restrict__ A, int lda,
    const float* __restrict__ Bw,
    float* __restrict__ C, int ldc,
    int N, int K, int epi,
    const float* __restrict__ bias,
    const float* __restrict__ resid)
{
    __shared__ short As[TM][TK];   // bf16 bits, 8 KB
    __shared__ short Bs[TN][TK];   // 8 KB
    const int tid  = threadIdx.x;
    const int lane = tid & 63;
    const int wave = tid >> 6;            // 0..3
    const int wm = (wave & 1) * 64;       // wave row offset
    const int wn = (wave >> 1) * 64;      // wave col offset
    const int bm = blockIdx.y * TM;
    const int bn = blockIdx.x * TN;

    floatx4 acc[4][4];
#pragma unroll
    for (int i = 0; i < 4; ++i)
#pragma unroll
        for (int j = 0; j < 4; ++j) acc[i][j] = (floatx4){0.f, 0.f, 0.f, 0.f};

    const int r0 = tid >> 3;        // 0..31 (row group)
    const int c4 = (tid & 7) * 4;   // fp32 col offset within k-tile

    const int fm = lane & 15;       // fragment row/col within 16x16
    const int q  = lane >> 4;       // k-quad: k = q*8 + j

    for (int k0 = 0; k0 < K; k0 += TK) {
        // stage A: 128x32 fp32 -> bf16 (4 float4 per thread)
#pragma unroll
        for (int i = 0; i < 4; ++i) {
            const int m = r0 + 32 * i;
            const float4 v = *(const float4*)&A[(size_t)(bm + m) * lda + k0 + c4];
            short4 h;
            h.x = f2bf(v.x); h.y = f2bf(v.y); h.z = f2bf(v.z); h.w = f2bf(v.w);
            *(short4*)&As[m][c4] = h;
        }
        // stage B: 128x32, guard ragged N (zeros beyond)
#pragma unroll
        for (int i = 0; i < 4; ++i) {
            const int n = r0 + 32 * i;
            const int gn = bn + n;
            short4 h;
            if (gn < N) {
                const float4 v = *(const float4*)&Bw[(size_t)gn * K + k0 + c4];
                h.x = f2bf(v.x); h.y = f2bf(v.y); h.z = f2bf(v.z); h.w = f2bf(v.w);
            } else {
                h.x = 0; h.y = 0; h.z = 0; h.w = 0;
            }
            *(short4*)&Bs[n][c4] = h;
        }
        __syncthreads();

        short8 af[4], bfr[4];
#pragma unroll
        for (int i = 0; i < 4; ++i)
            af[i] = *(short8*)&As[wm + i * 16 + fm][q * 8];
#pragma unroll
        for (int j = 0; j < 4; ++j)
            bfr[j] = *(short8*)&Bs[wn + j * 16 + fm][q * 8];
#pragma unroll
        for (int i = 0; i < 4; ++i)
#pragma unroll
            for (int j = 0; j < 4; ++j)
                acc[i][j] = __builtin_amdgcn_mfma_f32_16x16x32_bf16(
                    af[i], bfr[j], acc[i][j], 0, 0, 0);
        __syncthreads();
    }

    // epilogue: C/D layout col=lane&15, row=(lane>>4)*4+reg
    const int col = lane & 15;
    const int rq  = (lane >> 4) * 4;
#pragma unroll
    for (int i = 0; i < 4; ++i) {
#pragma unroll
        for (int j = 0; j < 4; ++j) {
#pragma unroll
            for (int r = 0; r < 4; ++r) {
                const int gm = bm + wm + i * 16 + rq + r;
                const int gn = bn + wn + j * 16 + col;
                if (gn >= N) continue;
                float v = acc[i][j][r];
                if (epi == 1) {
                    v += bias[gn];
                    v = fmaxf(v, 0.f) + log1pf(expf(-fabsf(v)));  // softplus
                } else if (epi == 2) {
                    v += resid[(size_t)gm * ldc + gn];
                }
                C[(size_t)gm * ldc + gn] = v;
            }
        }
    }
}

// ---------------- legacy vector GEMM (fallback path only) --------------------
#define BM 128
#define BN 128
#define BK 8

__global__ __launch_bounds__(256) void gemm_bt(
    const float* __restrict__ A, int lda,
    const float* __restrict__ Bw,
    float* __restrict__ C, int ldc,
    int M, int N, int K, int epi,
    const float* __restrict__ bias,
    const float* __restrict__ resid)
{
    __shared__ float As[BK][BM + 1];
    __shared__ float Bs[BK][BN + 1];
    const int tx = threadIdx.x, ty = threadIdx.y;
    const int tid = ty * 16 + tx;
    const int bm = blockIdx.y * BM, bn = blockIdx.x * BN;

    float acc[8][8];
#pragma unroll
    for (int i = 0; i < 8; ++i)
#pragma unroll
        for (int j = 0; j < 8; ++j) acc[i][j] = 0.f;

    for (int k0 = 0; k0 < K; k0 += BK) {
#pragma unroll
        for (int i = tid; i < BM * BK; i += 256) {
            const int m = i / BK, kk = i % BK;
            As[kk][m] = A[(size_t)(bm + m) * lda + (k0 + kk)];
        }
#pragma unroll
        for (int i = tid; i < BN * BK; i += 256) {
            const int n = i / BK, kk = i % BK;
            const int gn = bn + n;
            Bs[kk][n] = (gn < N) ? Bw[(size_t)gn * K + (k0 + kk)] : 0.f;
        }
        __syncthreads();
#pragma unroll
        for (int kk = 0; kk < BK; ++kk) {
            float av[8], bv[8];
#pragma unroll
            for (int i = 0; i < 8; ++i) av[i] = As[kk][ty * 8 + i];
#pragma unroll
            for (int j = 0; j < 8; ++j) bv[j] = Bs[kk][tx * 8 + j];
#pragma unroll
            for (int i = 0; i < 8; ++i)
#pragma unroll
                for (int j = 0; j < 8; ++j) acc[i][j] += av[i] * bv[j];
        }
        __syncthreads();
    }

#pragma unroll
    for (int i = 0; i < 8; ++i) {
        const int gm = bm + ty * 8 + i;
#pragma unroll
        for (int j = 0; j < 8; ++j) {
            const int gn = bn + tx * 8 + j;
            if (gn >= N) continue;
            float v = acc[i][j];
            if (epi == 1) {
                v += bias[gn];
                v = fmaxf(v, 0.f) + log1pf(expf(-fabsf(v)));
            } else if (epi == 2) {
                v += resid[(size_t)gm * ldc + gn];
            }
            C[(size_t)gm * ldc + gn] = v;
        }
    }
}

// ======================= parallel conv + 3-phase scan =========================

__global__ __launch_bounds__(256) void conv_par_kernel(
    const float* __restrict__ xz, const float* __restrict__ cw,
    const float* __restrict__ cb, float* __restrict__ uc)
{
    const int id = blockIdx.x * 256 + threadIdx.x;   // 0 .. B*L*D_INNER-1
    const int d = id & (D_INNER - 1);
    const int t = (id >> 11) & (LL - 1);
    const int b = id >> 22;
    const float* up = xz + (size_t)b * LL * XZ_LD + d;
    float acc = cb[d];
#pragma unroll
    for (int k = 0; k < 4; ++k) {
        const int tt = t - 3 + k;
        if (tt >= 0) acc += up[(size_t)tt * XZ_LD] * cw[d * 4 + k];
    }
    uc[(size_t)(b * LL + t) * D_INNER + d] = acc / (1.f + expf(-acc));
}

__global__ __launch_bounds__(256) void scan_p1(
    const float* __restrict__ uc, const float* __restrict__ dtb,
    const float* __restrict__ dbl, const float* __restrict__ A_log,
    float* __restrict__ Psum, float* __restrict__ Hloc)
{
    const int blk = blockIdx.x;
    const int d = (blk & 7) * 256 + threadIdx.x;
    const int c = (blk >> 3) & (NCH - 1);
    const int b = blk >> 8;
    float A[D_STATE], h[D_STATE];
#pragma unroll
    for (int n = 0; n < D_STATE; ++n) {
        A[n] = -expf(A_log[d * D_STATE + n]);
        h[n] = 0.f;
    }
    const size_t row0 = (size_t)b * LL + c * TCH;
    const float* dtp = dtb + row0 * D_INNER + d;
    const float* up  = uc  + row0 * D_INNER + d;
    const float* Bp  = dbl + row0 * DBL_LD + DT_RANK;
    float S = 0.f;
    for (int t = 0; t < TCH; ++t) {
        const float dtv = dtp[(size_t)t * D_INNER];
        const float uv  = up[(size_t)t * D_INNER];
        const float du  = dtv * uv;
        S += dtv;
#pragma unroll
        for (int n = 0; n < D_STATE; ++n)
            h[n] = expf(dtv * A[n]) * h[n] + du * Bp[(size_t)t * DBL_LD + n];
    }
    const size_t o = (((size_t)b * NCH + c) * D_INNER + d) * D_STATE;
#pragma unroll
    for (int n = 0; n < D_STATE; ++n) {
        Psum[o + n] = expf(S * A[n]);
        Hloc[o + n] = h[n];
    }
}

__global__ __launch_bounds__(256) void scan_p2(
    float* __restrict__ Psum, const float* __restrict__ Hloc)
{
    const int id = blockIdx.x * 256 + threadIdx.x;   // 0 .. B*D_INNER*16-1
    const int dn = id & (D_INNER * D_STATE - 1);
    const int b  = id >> 15;
    float h = 0.f;
    for (int c = 0; c < NCH; ++c) {
        const size_t o = ((size_t)(b * NCH + c) * D_INNER * D_STATE) + dn;
        const float P  = Psum[o];
        const float hl = Hloc[o];
        Psum[o] = h;          // Hin for chunk c
        h = P * h + hl;
    }
}

__global__ __launch_bounds__(256) void scan_p3(
    float* __restrict__ xz, const float* __restrict__ uc,
    const float* __restrict__ dtb, const float* __restrict__ dbl,
    const float* __restrict__ A_log, const float* __restrict__ Dw,
    const float* __restrict__ Hin)
{
    const int blk = blockIdx.x;
    const int d = (blk & 7) * 256 + threadIdx.x;
    const int c = (blk >> 3) & (NCH - 1);
    const int b = blk >> 8;
    float A[D_STATE], h[D_STATE];
    const size_t o = (((size_t)b * NCH + c) * D_INNER + d) * D_STATE;
#pragma unroll
    for (int n = 0; n < D_STATE; ++n) {
        A[n] = -expf(A_log[d * D_STATE + n]);
        h[n] = Hin[o + n];
    }
    const float Dd = Dw[d];
    const size_t row0 = (size_t)b * LL + c * TCH;
    const float* dtp = dtb + row0 * D_INNER + d;
    const float* up  = uc  + row0 * D_INNER + d;
    const float* BCp = dbl + row0 * DBL_LD;
    float* xzp = xz + ((size_t)b * LL + c * TCH) * XZ_LD + d;
    for (int t = 0; t < TCH; ++t) {
        const float dtv = dtp[(size_t)t * D_INNER];
        const float uv  = up[(size_t)t * D_INNER];
        const float du  = dtv * uv;
        float acc = uv * Dd;
        const float* Brow = BCp + (size_t)t * DBL_LD + DT_RANK;
        const float* Crow = Brow + D_STATE;
#pragma unroll
        for (int n = 0; n < D_STATE; ++n) {
            const float dA = expf(dtv * A[n]);
            h[n] = dA * h[n] + du * Brow[n];
            acc += h[n] * Crow[n];
        }
        const float zv = xzp[(size_t)t * XZ_LD + D_INNER];
        const float sz = zv / (1.f + expf(-zv));
        xzp[(size_t)t * XZ_LD] = acc * sz;   // y in place of raw u
    }
}

// ---------------- fallback (sequential) conv + scan --------------------------
__global__ __launch_bounds__(256) void conv_silu_kernel(
    float* __restrict__ xz, const float* __restrict__ cw,
    const float* __restrict__ cb)
{
    const int idx = blockIdx.x * 256 + threadIdx.x;
    const int b = idx >> 11, d = idx & (D_INNER - 1);
    const float w0 = cw[d * 4 + 0], w1 = cw[d * 4 + 1];
    const float w2 = cw[d * 4 + 2], w3 = cw[d * 4 + 3];
    const float bias = cb[d];
    float* u = xz + (size_t)b * LL * XZ_LD + d;
    float x0 = 0.f, x1 = 0.f, x2 = 0.f;
    for (int t = 0; t < LL; ++t) {
        const float x3 = u[(size_t)t * XZ_LD];
        const float c = bias + x0 * w0 + x1 * w1 + x2 * w2 + x3 * w3;
        u[(size_t)t * XZ_LD] = c / (1.f + expf(-c));
        x0 = x1; x1 = x2; x2 = x3;
    }
}

__global__ __launch_bounds__(256) void scan_kernel(
    float* __restrict__ xz, const float* __restrict__ dtb,
    const float* __restrict__ dbl,
    const float* __restrict__ A_log, const float* __restrict__ Dw)
{
    const int idx = blockIdx.x * 256 + threadIdx.x;
    const int b = idx >> 11, d = idx & (D_INNER - 1);
    float A[D_STATE], h[D_STATE];
#pragma unroll
    for (int n = 0; n < D_STATE; ++n) {
        A[n] = -expf(A_log[d * D_STATE + n]);
        h[n] = 0.f;
    }
    const float Dd = Dw[d];
    const float* dtp  = dtb + (size_t)b * LL * D_INNER + d;
    float*       up   = xz  + (size_t)b * LL * XZ_LD + d;
    const float* dblp = dbl + (size_t)b * LL * DBL_LD;
    for (int t = 0; t < LL; ++t) {
        const float dtv = dtp[(size_t)t * D_INNER];
        const float uv  = up[(size_t)t * XZ_LD];
        const float zv  = up[(size_t)t * XZ_LD + D_INNER];
        const float* Brow = dblp + (size_t)t * DBL_LD + DT_RANK;
        const float* Crow = Brow + D_STATE;
        const float du = dtv * uv;
        float acc = uv * Dd;
#pragma unroll
        for (int n = 0; n < D_STATE; ++n) {
            const float dA = expf(dtv * A[n]);
            h[n] = dA * h[n] + du * Brow[n];
            acc += h[n] * Crow[n];
        }
        const float sz = zv / (1.f + expf(-zv));
        up[(size_t)t * XZ_LD] = acc * sz;
    }
}

extern "C" void kernel_launch(void* const* d_in, const int* in_sizes, int n_in,
                              void* d_out, int out_size, void* d_ws, size_t ws_size,
                              hipStream_t stream)
{
    const float* x       = (const float*)d_in[0];
    const float* ln_w    = (const float*)d_in[1];
    const float* ln_b    = (const float*)d_in[2];
    const float* W_in    = (const float*)d_in[3];
    const float* conv_w  = (const float*)d_in[4];
    const float* conv_b  = (const float*)d_in[5];
    const float* W_xproj = (const float*)d_in[6];
    const float* W_dt    = (const float*)d_in[7];
    const float* b_dt    = (const float*)d_in[8];
    const float* A_log   = (const float*)d_in[9];
    const float* Dw      = (const float*)d_in[10];
    const float* W_out   = (const float*)d_in[11];
    float* out = (float*)d_out;

    // ws layout (fp32):
    //   [dtb 8.39M | xz 16.78M | dbl 0.39M | uc 8.39M | Psum 2.10M | Hloc 2.10M]
    // xn aliases dtb (disjoint lifetimes). Fast path needs 145.5 MiB.
    float* dtb  = (float*)d_ws;
    float* xn   = dtb;
    float* xz   = dtb + (size_t)BL * D_INNER;
    float* dbl  = xz  + (size_t)BL * XZ_LD;
    float* uc   = dbl + (size_t)BL * DBL_LD;
    float* Psum = uc  + (size_t)BL * D_INNER;
    float* Hloc = Psum + (size_t)BB * NCH * D_INNER * D_STATE;
    const size_t need_floats =
        (size_t)BL * D_INNER + (size_t)BL * XZ_LD + (size_t)BL * DBL_LD +
        (size_t)BL * D_INNER + 2 * (size_t)BB * NCH * D_INNER * D_STATE;
    const bool fast = ws_size >= need_floats * sizeof(float);

    // 1. LayerNorm
    ln_kernel<<<BL, 256, 0, stream>>>(x, ln_w, ln_b, xn);

    if (fast) {
        // 2. xz = xn @ W_in^T   (M=4096, N=4096, K=1024)  [MFMA]
        gemm_mfma<<<dim3(XZ_LD / TN, BL / TM), 256, 0, stream>>>(
            xn, D_MODEL, W_in, xz, XZ_LD, XZ_LD, D_MODEL, 0, nullptr, nullptr);
        // 3. parallel conv+SiLU: raw u (xz) -> uc
        conv_par_kernel<<<(size_t)BL * D_INNER / 256, 256, 0, stream>>>(
            xz, conv_w, conv_b, uc);
        // 4. dbl = uc @ W_xproj^T  (M=4096, N=96, K=2048)  [MFMA, ragged N]
        gemm_mfma<<<dim3(1, BL / TM), 256, 0, stream>>>(
            uc, D_INNER, W_xproj, dbl, DBL_LD, DBL_LD, D_INNER, 0, nullptr, nullptr);
        // 5. dt = softplus(dt_r @ W_dt^T + b_dt)  (M=4096, N=2048, K=64) [MFMA]
        gemm_mfma<<<dim3(D_INNER / TN, BL / TM), 256, 0, stream>>>(
            dbl, DBL_LD, W_dt, dtb, D_INNER, D_INNER, DT_RANK, 1, b_dt, nullptr);
        // 6. chunked parallel scan; y -> raw-u columns of xz
        scan_p1<<<BB * NCH * 8, 256, 0, stream>>>(uc, dtb, dbl, A_log, Psum, Hloc);
        scan_p2<<<BB * D_INNER * D_STATE / 256, 256, 0, stream>>>(Psum, Hloc);
        scan_p3<<<BB * NCH * 8, 256, 0, stream>>>(xz, uc, dtb, dbl, A_log, Dw, Psum);
        // 7. out = y @ W_out^T + x  (M=4096, N=1024, K=2048)  [MFMA]
        gemm_mfma<<<dim3(D_MODEL / TN, BL / TM), 256, 0, stream>>>(
            xz, XZ_LD, W_out, out, D_MODEL, D_MODEL, D_INNER, 2, nullptr, x);
    } else {
        dim3 blk(16, 16);
        gemm_bt<<<dim3(XZ_LD / BN, BL / BM), blk, 0, stream>>>(
            xn, D_MODEL, W_in, xz, XZ_LD, BL, XZ_LD, D_MODEL, 0, nullptr, nullptr);
        conv_silu_kernel<<<(BB * D_INNER) / 256, 256, 0, stream>>>(xz, conv_w, conv_b);
        gemm_bt<<<dim3(1, BL / BM), blk, 0, stream>>>(
            xz, XZ_LD, W_xproj, dbl, DBL_LD, BL, DBL_LD, D_INNER, 0, nullptr, nullptr);
        gemm_bt<<<dim3(D_INNER / BN, BL / BM), blk, 0, stream>>>(
            dbl, DBL_LD, W_dt, dtb, D_INNER, BL, D_INNER, DT_RANK, 1, b_dt, nullptr);
        scan_kernel<<<(BB * D_INNER) / 256, 256, 0, stream>>>(xz, dtb, dbl, A_log, Dw);
        gemm_bt<<<dim3(D_MODEL / BN, BL / BM), blk, 0, stream>>>(
            xz, XZ_LD, W_out, out, D_MODEL, BL, D_MODEL, D_INNER, 2, nullptr, x);
    }
}

// Round 8
// 523.199 us; speedup vs baseline: 12.8178x; 1.8325x over previous
//
#include <hip/hip_runtime.h>
#include <hip/hip_bf16.h>
#include <stdint.h>

typedef __hip_bfloat16 bf16;
typedef __attribute__((ext_vector_type(8))) short short8;
typedef __attribute__((ext_vector_type(4))) float floatx4;

#define D_MODEL 1024
#define D_STATE 16
#define D_INNER 2048
#define DT_RANK 64
#define BB 2
#define LL 2048
#define BL (BB * LL)            // 4096 rows
#define XZ_LD (2 * D_INNER)     // 4096 (fallback path only)
#define DBL_LD (DT_RANK + 2 * D_STATE)  // 96
#define NCH 32                  // time chunks for parallel scan
#define TCH (LL / NCH)          // 64 steps per chunk

__device__ __forceinline__ bf16 f2b(float f) { return __float2bfloat16(f); }

// async 16B global -> LDS (wave-uniform LDS base + lane*16; rows contiguous)
__device__ __forceinline__ void gload16(const void* g, void* l) {
    __builtin_amdgcn_global_load_lds(
        (const __attribute__((address_space(1))) uint32_t*)(uintptr_t)g,
        (__attribute__((address_space(3))) uint32_t*)(uintptr_t)l,
        16, 0, 0);
}

// ---------------- LayerNorm: one block per row; bf16 and/or fp32 out ---------
__global__ __launch_bounds__(256) void ln_kernel(
    const float* __restrict__ x, const float* __restrict__ w,
    const float* __restrict__ b, float* __restrict__ xnf, bf16* __restrict__ xnb)
{
    __shared__ float s1[256], s2[256];
    const int row = blockIdx.x;
    const int tid = threadIdx.x;
    const float* xr = x + (size_t)row * D_MODEL;
    float v[4], sum = 0.f, sq = 0.f;
#pragma unroll
    for (int i = 0; i < 4; ++i) {
        v[i] = xr[tid + 256 * i];
        sum += v[i];
        sq  += v[i] * v[i];
    }
    s1[tid] = sum; s2[tid] = sq;
    __syncthreads();
    for (int s = 128; s > 0; s >>= 1) {
        if (tid < s) { s1[tid] += s1[tid + s]; s2[tid] += s2[tid + s]; }
        __syncthreads();
    }
    const float mu  = s1[0] * (1.f / D_MODEL);
    const float var = s2[0] * (1.f / D_MODEL) - mu * mu;
    const float rs  = rsqrtf(var + 1e-5f);
#pragma unroll
    for (int i = 0; i < 4; ++i) {
        const int c = tid + 256 * i;
        const float r = (v[i] - mu) * rs * w[c] + b[c];
        if (xnb) xnb[(size_t)row * D_MODEL + c] = f2b(r);
        if (xnf) xnf[(size_t)row * D_MODEL + c] = r;
    }
}

// --------- fused fp32->bf16 weight conversion (+pad W_xproj, +zero dbl) ------
#define S0 (4096 * 1024)   // W_in
#define S1 (128 * 2048)    // W_xproj padded to 128 rows
#define S2 (2048 * 64)     // W_dt
#define S3 (1024 * 2048)   // W_out
#define S4 (BL * DBL_LD)   // dbl zero-init (for split-K atomics)

__global__ __launch_bounds__(256) void wcvt_kernel(
    const float* __restrict__ Win, const float* __restrict__ Wx,
    const float* __restrict__ Wdt, const float* __restrict__ Wout,
    bf16* __restrict__ win_bf, bf16* __restrict__ wx_bf,
    bf16* __restrict__ wdt_bf, bf16* __restrict__ wout_bf,
    float* __restrict__ dbl)
{
    int id = blockIdx.x * 256 + threadIdx.x;
    if (id < S0) { win_bf[id] = f2b(Win[id]); return; }
    id -= S0;
    if (id < S1) { wx_bf[id] = (id < 96 * 2048) ? f2b(Wx[id]) : f2b(0.f); return; }
    id -= S1;
    if (id < S2) { wdt_bf[id] = f2b(Wdt[id]); return; }
    id -= S2;
    if (id < S3) { wout_bf[id] = f2b(Wout[id]); return; }
    id -= S3;
    dbl[id] = 0.f;
}

// ============ bf16 MFMA GEMM (m97-style): C = A[M,K] * B[N,K]^T ==============
// epi: 1=+bias softplus; 2=+resid; 3=atomicAdd (split-K, K=slice len);
//      4=u/z split (gn<D_INNER -> fp32 C, else bf16 C2)
#define GTM 128
#define GTN 128
#define GTK 32

__global__ __launch_bounds__(256) void gemm_bf(
    const bf16* __restrict__ A, int lda,
    const bf16* __restrict__ B, int ldb,
    float* __restrict__ C, int ldc,
    int N, int K, int epi,
    const float* __restrict__ bias,
    const float* __restrict__ resid,
    bf16* __restrict__ C2)
{
    __shared__ short As[GTM * GTK];   // 8 KB
    __shared__ short Bs[GTN * GTK];   // 8 KB
    const int tid  = threadIdx.x;
    const int lane = tid & 63;
    const int wave = tid >> 6;            // 0..3
    const int wm = (wave & 1) * 64;
    const int wn = (wave >> 1) * 64;
    const int bm = blockIdx.y * GTM;
    const int bn = blockIdx.x * GTN;
    const int kbase = blockIdx.z * K;     // split-K base (K = slice length)

    floatx4 acc[4][4];
#pragma unroll
    for (int i = 0; i < 4; ++i)
#pragma unroll
        for (int j = 0; j < 4; ++j) acc[i][j] = (floatx4){0.f, 0.f, 0.f, 0.f};

    const int srow = wave * 16 + (lane >> 2);   // 0..63 (per pass)
    const int scol = (lane & 3) * 8;            // bf16 col within k-tile
    const int fm = lane & 15;
    const int q  = lane >> 4;

    for (int k0 = 0; k0 < K; k0 += GTK) {
#pragma unroll
        for (int r = 0; r < 2; ++r) {
            const int m = r * 64 + srow;
            gload16(A + (size_t)(bm + m) * lda + kbase + k0 + scol,
                    As + m * GTK + scol);
            gload16(B + (size_t)(bn + m) * ldb + kbase + k0 + scol,
                    Bs + m * GTK + scol);
        }
        __syncthreads();

        short8 af[4], bfr[4];
#pragma unroll
        for (int i = 0; i < 4; ++i)
            af[i] = *(short8*)&As[(wm + i * 16 + fm) * GTK + q * 8];
#pragma unroll
        for (int j = 0; j < 4; ++j)
            bfr[j] = *(short8*)&Bs[(wn + j * 16 + fm) * GTK + q * 8];
#pragma unroll
        for (int i = 0; i < 4; ++i)
#pragma unroll
            for (int j = 0; j < 4; ++j)
                acc[i][j] = __builtin_amdgcn_mfma_f32_16x16x32_bf16(
                    af[i], bfr[j], acc[i][j], 0, 0, 0);
        __syncthreads();
    }

    const int col = lane & 15;
    const int rq  = (lane >> 4) * 4;
#pragma unroll
    for (int i = 0; i < 4; ++i) {
#pragma unroll
        for (int j = 0; j < 4; ++j) {
#pragma unroll
            for (int r = 0; r < 4; ++r) {
                const int gm = bm + wm + i * 16 + rq + r;
                const int gn = bn + wn + j * 16 + col;
                if (gn >= N) continue;
                float v = acc[i][j][r];
                if (epi == 1) {
                    v += bias[gn];
                    v = fmaxf(v, 0.f) + log1pf(expf(-fabsf(v)));
                    C[(size_t)gm * ldc + gn] = v;
                } else if (epi == 2) {
                    C[(size_t)gm * ldc + gn] = v + resid[(size_t)gm * ldc + gn];
                } else if (epi == 3) {
                    atomicAdd(&C[(size_t)gm * ldc + gn], v);
                } else {
                    if (gn < D_INNER) C[(size_t)gm * ldc + gn] = v;
                    else C2[(size_t)gm * (size_t)D_INNER + (gn - D_INNER)] = f2b(v);
                }
            }
        }
    }
}

// ------------- conv(4)+SiLU from contiguous uraw; fp32 + bf16 out -----------
__global__ __launch_bounds__(256) void conv_par3(
    const float* __restrict__ uraw, const float* __restrict__ cw,
    const float* __restrict__ cb, float* __restrict__ uc, bf16* __restrict__ ucb)
{
    const int id = blockIdx.x * 256 + threadIdx.x;  // = (b*LL+t)*D_INNER+d
    const int d = id & (D_INNER - 1);
    const int t = (id >> 11) & (LL - 1);
    float acc = cb[d];
#pragma unroll
    for (int k = 0; k < 4; ++k) {
        const int tt = t - 3 + k;
        if (tt >= 0) acc += uraw[(size_t)id + (size_t)(k - 3) * D_INNER] * cw[d * 4 + k];
    }
    const float s = acc / (1.f + expf(-acc));
    uc[id] = s;
    ucb[id] = f2b(s);
}

// ------------- dbl[:, :64] -> bf16 dt_r copy for GEMM-5 ----------------------
__global__ __launch_bounds__(256) void cvt_dtr(
    const float* __restrict__ dbl, bf16* __restrict__ dtr_bf)
{
    const int id = blockIdx.x * 256 + threadIdx.x;  // m*64+r
    const int m = id >> 6, r = id & 63;
    dtr_bf[id] = f2b(dbl[(size_t)m * DBL_LD + r]);
}

// ------------------------------ 3-phase scan ---------------------------------
__global__ __launch_bounds__(256) void scan_p1(
    const float* __restrict__ uc, const float* __restrict__ dtb,
    const float* __restrict__ dbl, const float* __restrict__ A_log,
    float* __restrict__ Psum, float* __restrict__ Hloc)
{
    const int blk = blockIdx.x;
    const int d = (blk & 7) * 256 + threadIdx.x;
    const int c = (blk >> 3) & (NCH - 1);
    const int b = blk >> 8;
    float A[D_STATE], h[D_STATE];
#pragma unroll
    for (int n = 0; n < D_STATE; ++n) {
        A[n] = -expf(A_log[d * D_STATE + n]);
        h[n] = 0.f;
    }
    const size_t row0 = (size_t)b * LL + c * TCH;
    const float* dtp = dtb + row0 * D_INNER + d;
    const float* up  = uc  + row0 * D_INNER + d;
    const float* Bp  = dbl + row0 * DBL_LD + DT_RANK;
    float S = 0.f;
    for (int t = 0; t < TCH; ++t) {
        const float dtv = dtp[(size_t)t * D_INNER];
        const float uv  = up[(size_t)t * D_INNER];
        const float du  = dtv * uv;
        S += dtv;
#pragma unroll
        for (int n = 0; n < D_STATE; ++n)
            h[n] = expf(dtv * A[n]) * h[n] + du * Bp[(size_t)t * DBL_LD + n];
    }
    const size_t o = (((size_t)b * NCH + c) * D_INNER + d) * D_STATE;
#pragma unroll
    for (int n = 0; n < D_STATE; ++n) {
        Psum[o + n] = expf(S * A[n]);
        Hloc[o + n] = h[n];
    }
}

__global__ __launch_bounds__(256) void scan_p2(
    float* __restrict__ Psum, const float* __restrict__ Hloc)
{
    const int id = blockIdx.x * 256 + threadIdx.x;
    const int dn = id & (D_INNER * D_STATE - 1);
    const int b  = id >> 15;
    float h = 0.f;
    for (int c = 0; c < NCH; ++c) {
        const size_t o = ((size_t)(b * NCH + c) * D_INNER * D_STATE) + dn;
        const float P  = Psum[o];
        const float hl = Hloc[o];
        Psum[o] = h;          // Hin for chunk c
        h = P * h + hl;
    }
}

__global__ __launch_bounds__(256) void scan_p3b(
    const float* __restrict__ uc, const float* __restrict__ dtb,
    const float* __restrict__ dbl, const float* __restrict__ A_log,
    const float* __restrict__ Dw, const float* __restrict__ Hin,
    const bf16* __restrict__ zbf, bf16* __restrict__ ybf)
{
    const int blk = blockIdx.x;
    const int d = (blk & 7) * 256 + threadIdx.x;
    const int c = (blk >> 3) & (NCH - 1);
    const int b = blk >> 8;
    float A[D_STATE], h[D_STATE];
    const size_t o = (((size_t)b * NCH + c) * D_INNER + d) * D_STATE;
#pragma unroll
    for (int n = 0; n < D_STATE; ++n) {
        A[n] = -expf(A_log[d * D_STATE + n]);
        h[n] = Hin[o + n];
    }
    const float Dd = Dw[d];
    const size_t row0 = (size_t)b * LL + c * TCH;
    const float* dtp = dtb + row0 * D_INNER + d;
    const float* up  = uc  + row0 * D_INNER + d;
    const float* BCp = dbl + row0 * DBL_LD;
    const bf16* zp   = zbf + row0 * D_INNER + d;
    bf16* yp         = ybf + row0 * D_INNER + d;
    for (int t = 0; t < TCH; ++t) {
        const float dtv = dtp[(size_t)t * D_INNER];
        const float uv  = up[(size_t)t * D_INNER];
        const float du  = dtv * uv;
        float acc = uv * Dd;
        const float* Brow = BCp + (size_t)t * DBL_LD + DT_RANK;
        const float* Crow = Brow + D_STATE;
#pragma unroll
        for (int n = 0; n < D_STATE; ++n) {
            const float dA = expf(dtv * A[n]);
            h[n] = dA * h[n] + du * Brow[n];
            acc += h[n] * Crow[n];
        }
        const float zv = (float)zp[(size_t)t * D_INNER];
        const float sz = zv / (1.f + expf(-zv));
        yp[(size_t)t * D_INNER] = f2b(acc * sz);
    }
}

// ---------------- fallback (small ws): R4 sequential path --------------------
#define BM 128
#define BN 128
#define BK 8

__global__ __launch_bounds__(256) void gemm_bt(
    const float* __restrict__ A, int lda,
    const float* __restrict__ Bw,
    float* __restrict__ C, int ldc,
    int M, int N, int K, int epi,
    const float* __restrict__ bias,
    const float* __restrict__ resid)
{
    __shared__ float As[BK][BM + 1];
    __shared__ float Bs[BK][BN + 1];
    const int tx = threadIdx.x, ty = threadIdx.y;
    const int tid = ty * 16 + tx;
    const int bm = blockIdx.y * BM, bn = blockIdx.x * BN;
    float acc[8][8];
#pragma unroll
    for (int i = 0; i < 8; ++i)
#pragma unroll
        for (int j = 0; j < 8; ++j) acc[i][j] = 0.f;
    for (int k0 = 0; k0 < K; k0 += BK) {
#pragma unroll
        for (int i = tid; i < BM * BK; i += 256) {
            const int m = i / BK, kk = i % BK;
            As[kk][m] = A[(size_t)(bm + m) * lda + (k0 + kk)];
        }
#pragma unroll
        for (int i = tid; i < BN * BK; i += 256) {
            const int n = i / BK, kk = i % BK;
            const int gn = bn + n;
            Bs[kk][n] = (gn < N) ? Bw[(size_t)gn * K + (k0 + kk)] : 0.f;
        }
        __syncthreads();
#pragma unroll
        for (int kk = 0; kk < BK; ++kk) {
            float av[8], bv[8];
#pragma unroll
            for (int i = 0; i < 8; ++i) av[i] = As[kk][ty * 8 + i];
#pragma unroll
            for (int j = 0; j < 8; ++j) bv[j] = Bs[kk][tx * 8 + j];
#pragma unroll
            for (int i = 0; i < 8; ++i)
#pragma unroll
                for (int j = 0; j < 8; ++j) acc[i][j] += av[i] * bv[j];
        }
        __syncthreads();
    }
#pragma unroll
    for (int i = 0; i < 8; ++i) {
        const int gm = bm + ty * 8 + i;
#pragma unroll
        for (int j = 0; j < 8; ++j) {
            const int gn = bn + tx * 8 + j;
            if (gn >= N) continue;
            float v = acc[i][j];
            if (epi == 1) {
                v += bias[gn];
                v = fmaxf(v, 0.f) + log1pf(expf(-fabsf(v)));
            } else if (epi == 2) {
                v += resid[(size_t)gm * ldc + gn];
            }
            C[(size_t)gm * ldc + gn] = v;
        }
    }
}

__global__ __launch_bounds__(256) void conv_silu_kernel(
    float* __restrict__ xz, const float* __restrict__ cw,
    const float* __restrict__ cb)
{
    const int idx = blockIdx.x * 256 + threadIdx.x;
    const int b = idx >> 11, d = idx & (D_INNER - 1);
    const float w0 = cw[d * 4 + 0], w1 = cw[d * 4 + 1];
    const float w2 = cw[d * 4 + 2], w3 = cw[d * 4 + 3];
    const float bias = cb[d];
    float* u = xz + (size_t)b * LL * XZ_LD + d;
    float x0 = 0.f, x1 = 0.f, x2 = 0.f;
    for (int t = 0; t < LL; ++t) {
        const float x3 = u[(size_t)t * XZ_LD];
        const float c = bias + x0 * w0 + x1 * w1 + x2 * w2 + x3 * w3;
        u[(size_t)t * XZ_LD] = c / (1.f + expf(-c));
        x0 = x1; x1 = x2; x2 = x3;
    }
}

__global__ __launch_bounds__(256) void scan_kernel(
    float* __restrict__ xz, const float* __restrict__ dtb,
    const float* __restrict__ dbl,
    const float* __restrict__ A_log, const float* __restrict__ Dw)
{
    const int idx = blockIdx.x * 256 + threadIdx.x;
    const int b = idx >> 11, d = idx & (D_INNER - 1);
    float A[D_STATE], h[D_STATE];
#pragma unroll
    for (int n = 0; n < D_STATE; ++n) {
        A[n] = -expf(A_log[d * D_STATE + n]);
        h[n] = 0.f;
    }
    const float Dd = Dw[d];
    const float* dtp  = dtb + (size_t)b * LL * D_INNER + d;
    float*       up   = xz  + (size_t)b * LL * XZ_LD + d;
    const float* dblp = dbl + (size_t)b * LL * DBL_LD;
    for (int t = 0; t < LL; ++t) {
        const float dtv = dtp[(size_t)t * D_INNER];
        const float uv  = up[(size_t)t * XZ_LD];
        const float zv  = up[(size_t)t * XZ_LD + D_INNER];
        const float* Brow = dblp + (size_t)t * DBL_LD + DT_RANK;
        const float* Crow = Brow + D_STATE;
        const float du = dtv * uv;
        float acc = uv * Dd;
#pragma unroll
        for (int n = 0; n < D_STATE; ++n) {
            const float dA = expf(dtv * A[n]);
            h[n] = dA * h[n] + du * Brow[n];
            acc += h[n] * Crow[n];
        }
        const float sz = zv / (1.f + expf(-zv));
        up[(size_t)t * XZ_LD] = acc * sz;
    }
}

extern "C" void kernel_launch(void* const* d_in, const int* in_sizes, int n_in,
                              void* d_out, int out_size, void* d_ws, size_t ws_size,
                              hipStream_t stream)
{
    const float* x       = (const float*)d_in[0];
    const float* ln_w    = (const float*)d_in[1];
    const float* ln_b    = (const float*)d_in[2];
    const float* W_in    = (const float*)d_in[3];
    const float* conv_w  = (const float*)d_in[4];
    const float* conv_b  = (const float*)d_in[5];
    const float* W_xproj = (const float*)d_in[6];
    const float* W_dt    = (const float*)d_in[7];
    const float* b_dt    = (const float*)d_in[8];
    const float* A_log   = (const float*)d_in[9];
    const float* Dw      = (const float*)d_in[10];
    const float* W_out   = (const float*)d_in[11];
    float* out = (float*)d_out;

    // big-path ws layout (float offsets from base). R7 BUG was zbf sized
    // 2097152 f; z is [4096x2048] bf16 = 4194304 f. Fixed offsets:
    //   dtb   [0,        8388608)   dt; early alias: xn_bf | win_bf
    //   uraw  [8388608, 16777216)   G2 u-out; later alias: Psum|Hloc|dtr_bf
    //   zbf   [16777216, 20971520)  bf16 z (4194304 f)   <-- was 2097152
    //   dbl   [20971520, 21364736)
    //   uc    [21364736, 29753344)
    //   ucy   [29753344, 33947648)  bf16 uc, then bf16 y
    //   wx_bf [33947648, 34078720) | wdt_bf [.., 34144256) | wout_bf [.., 35192832)
    // total = 35192832 f = 134.3 MiB  (< the >=145.5 MiB proven in R5)
    float* wsf    = (float*)d_ws;
    float* dtb    = wsf;
    bf16*  xn_bf  = (bf16*)dtb;
    bf16*  win_bf = (bf16*)(dtb + 2097152);
    float* uraw   = wsf + 8388608;
    float* Psum   = uraw;
    float* Hloc   = uraw + 2097152;
    bf16*  dtr_bf = (bf16*)(uraw + 4194304);
    bf16*  zbf    = (bf16*)(wsf + 16777216);
    float* dbl    = wsf + 20971520;
    float* uc     = wsf + 21364736;
    bf16*  ucy    = (bf16*)(wsf + 29753344);
    bf16*  wx_bf  = (bf16*)(wsf + 33947648);
    bf16*  wdt_bf = wx_bf + S1;
    bf16*  wout_bf= wdt_bf + S2;
    const size_t need_big = (size_t)35192832 * sizeof(float);

    if (ws_size >= need_big) {
        wcvt_kernel<<<(S0 + S1 + S2 + S3 + S4) / 256, 256, 0, stream>>>(
            W_in, W_xproj, W_dt, W_out, win_bf, wx_bf, wdt_bf, wout_bf, dbl);
        ln_kernel<<<BL, 256, 0, stream>>>(x, ln_w, ln_b, nullptr, xn_bf);
        // G2: [u|z] = xn @ W_in^T  (M=4096, N=4096, K=1024)
        gemm_bf<<<dim3(XZ_LD / GTN, BL / GTM, 1), 256, 0, stream>>>(
            xn_bf, D_MODEL, win_bf, D_MODEL, uraw, D_INNER,
            XZ_LD, D_MODEL, 4, nullptr, nullptr, zbf);
        conv_par3<<<(size_t)BL * D_INNER / 256, 256, 0, stream>>>(
            uraw, conv_w, conv_b, uc, ucy);
        // G4: dbl += uc @ W_xproj^T  (N=96 pad 128, split-K=8, atomic)
        gemm_bf<<<dim3(1, BL / GTM, 8), 256, 0, stream>>>(
            ucy, D_INNER, wx_bf, D_INNER, dbl, DBL_LD,
            DBL_LD, D_INNER / 8, 3, nullptr, nullptr, nullptr);
        cvt_dtr<<<BL * DT_RANK / 256, 256, 0, stream>>>(dbl, dtr_bf);
        // G5: dt = softplus(dt_r @ W_dt^T + b_dt)  (N=2048, K=64)
        gemm_bf<<<dim3(D_INNER / GTN, BL / GTM, 1), 256, 0, stream>>>(
            dtr_bf, DT_RANK, wdt_bf, DT_RANK, dtb, D_INNER,
            D_INNER, DT_RANK, 1, b_dt, nullptr, nullptr);
        scan_p1<<<BB * NCH * 8, 256, 0, stream>>>(uc, dtb, dbl, A_log, Psum, Hloc);
        scan_p2<<<BB * D_INNER * D_STATE / 256, 256, 0, stream>>>(Psum, Hloc);
        scan_p3b<<<BB * NCH * 8, 256, 0, stream>>>(
            uc, dtb, dbl, A_log, Dw, Psum, zbf, ucy);
        // G7: out = y @ W_out^T + x  (N=1024, K=2048)
        gemm_bf<<<dim3(D_MODEL / GTN, BL / GTM, 1), 256, 0, stream>>>(
            ucy, D_INNER, wout_bf, D_INNER, out, D_MODEL,
            D_MODEL, D_INNER, 2, nullptr, x, nullptr);
    } else {
        float* fdtb = wsf;
        float* fxn  = fdtb;
        float* fxz  = fdtb + (size_t)BL * D_INNER;
        float* fdbl = fxz + (size_t)BL * XZ_LD;
        ln_kernel<<<BL, 256, 0, stream>>>(x, ln_w, ln_b, fxn, nullptr);
        dim3 blk(16, 16);
        gemm_bt<<<dim3(XZ_LD / BN, BL / BM), blk, 0, stream>>>(
            fxn, D_MODEL, W_in, fxz, XZ_LD, BL, XZ_LD, D_MODEL, 0, nullptr, nullptr);
        conv_silu_kernel<<<(BB * D_INNER) / 256, 256, 0, stream>>>(fxz, conv_w, conv_b);
        gemm_bt<<<dim3(1, BL / BM), blk, 0, stream>>>(
            fxz, XZ_LD, W_xproj, fdbl, DBL_LD, BL, DBL_LD, D_INNER, 0, nullptr, nullptr);
        gemm_bt<<<dim3(D_INNER / BN, BL / BM), blk, 0, stream>>>(
            fdbl, DBL_LD, W_dt, fdtb, D_INNER, BL, D_INNER, DT_RANK, 1, b_dt, nullptr);
        scan_kernel<<<(BB * D_INNER) / 256, 256, 0, stream>>>(fxz, fdtb, fdbl, A_log, Dw);
        gemm_bt<<<dim3(D_MODEL / BN, BL / BM), blk, 0, stream>>>(
            fxz, XZ_LD, W_out, out, D_MODEL, BL, D_MODEL, D_INNER, 2, nullptr, x);
    }
}

// Round 9
// 430.673 us; speedup vs baseline: 15.5716x; 1.2148x over previous
//
#include <hip/hip_runtime.h>
#include <hip/hip_bf16.h>
#include <stdint.h>

typedef __hip_bfloat16 bf16;
typedef __attribute__((ext_vector_type(8))) short short8;
typedef __attribute__((ext_vector_type(4))) float floatx4;

#define D_MODEL 1024
#define D_STATE 16
#define D_INNER 2048
#define DT_RANK 64
#define BB 2
#define LL 2048
#define BL (BB * LL)            // 4096 rows
#define XZ_LD (2 * D_INNER)     // 4096 (fallback path only)
#define DBL_LD (DT_RANK + 2 * D_STATE)  // 96
#define NCH 32                  // time chunks for parallel scan
#define TCH (LL / NCH)          // 64 steps per chunk

__device__ __forceinline__ bf16 f2b(float f) { return __float2bfloat16(f); }

// fast sigmoid / softplus via native v_exp/v_log/v_rcp (~3e-7 rel err)
__device__ __forceinline__ float fsig(float v)  { return __fdividef(1.f, 1.f + __expf(-v)); }
__device__ __forceinline__ float fsoftp(float v){ return fmaxf(v, 0.f) + __logf(1.f + __expf(-fabsf(v))); }

// async 16B global -> LDS (wave-uniform LDS base + lane*16; rows contiguous)
__device__ __forceinline__ void gload16(const void* g, void* l) {
    __builtin_amdgcn_global_load_lds(
        (const __attribute__((address_space(1))) uint32_t*)(uintptr_t)g,
        (__attribute__((address_space(3))) uint32_t*)(uintptr_t)l,
        16, 0, 0);
}

// ---------------- LayerNorm: one block per row; bf16 and/or fp32 out ---------
__global__ __launch_bounds__(256) void ln_kernel(
    const float* __restrict__ x, const float* __restrict__ w,
    const float* __restrict__ b, float* __restrict__ xnf, bf16* __restrict__ xnb)
{
    __shared__ float s1[256], s2[256];
    const int row = blockIdx.x;
    const int tid = threadIdx.x;
    const float* xr = x + (size_t)row * D_MODEL;
    float v[4], sum = 0.f, sq = 0.f;
#pragma unroll
    for (int i = 0; i < 4; ++i) {
        v[i] = xr[tid + 256 * i];
        sum += v[i];
        sq  += v[i] * v[i];
    }
    s1[tid] = sum; s2[tid] = sq;
    __syncthreads();
    for (int s = 128; s > 0; s >>= 1) {
        if (tid < s) { s1[tid] += s1[tid + s]; s2[tid] += s2[tid + s]; }
        __syncthreads();
    }
    const float mu  = s1[0] * (1.f / D_MODEL);
    const float var = s2[0] * (1.f / D_MODEL) - mu * mu;
    const float rs  = rsqrtf(var + 1e-5f);
#pragma unroll
    for (int i = 0; i < 4; ++i) {
        const int c = tid + 256 * i;
        const float r = (v[i] - mu) * rs * w[c] + b[c];
        if (xnb) xnb[(size_t)row * D_MODEL + c] = f2b(r);
        if (xnf) xnf[(size_t)row * D_MODEL + c] = r;
    }
}

// ------------- out pre-init with residual x (for G7 split-K atomics) ---------
__global__ __launch_bounds__(256) void init_out(
    const float* __restrict__ x, float* __restrict__ out)
{
    const int id = blockIdx.x * 256 + threadIdx.x;
    ((float4*)out)[id] = ((const float4*)x)[id];
}

// --------- fused fp32->bf16 weight conversion (+pad W_xproj, +zero dbl) ------
#define S0 (4096 * 1024)   // W_in
#define S1 (128 * 2048)    // W_xproj padded to 128 rows
#define S2 (2048 * 64)     // W_dt
#define S3 (1024 * 2048)   // W_out
#define S4 (BL * DBL_LD)   // dbl zero-init (for split-K atomics)

__global__ __launch_bounds__(256) void wcvt_kernel(
    const float* __restrict__ Win, const float* __restrict__ Wx,
    const float* __restrict__ Wdt, const float* __restrict__ Wout,
    bf16* __restrict__ win_bf, bf16* __restrict__ wx_bf,
    bf16* __restrict__ wdt_bf, bf16* __restrict__ wout_bf,
    float* __restrict__ dbl)
{
    int id = blockIdx.x * 256 + threadIdx.x;
    if (id < S0) { win_bf[id] = f2b(Win[id]); return; }
    id -= S0;
    if (id < S1) { wx_bf[id] = (id < 96 * 2048) ? f2b(Wx[id]) : f2b(0.f); return; }
    id -= S1;
    if (id < S2) { wdt_bf[id] = f2b(Wdt[id]); return; }
    id -= S2;
    if (id < S3) { wout_bf[id] = f2b(Wout[id]); return; }
    id -= S3;
    dbl[id] = 0.f;
}

// ============ bf16 MFMA GEMM (m97-style): C = A[M,K] * B[N,K]^T ==============
// epi: 1=+bias softplus; 2=+resid; 3=atomicAdd (split-K, K=slice len);
//      4=u/z split (gn<D_INNER -> fp32 C, else bf16 C2)
#define GTM 128
#define GTN 128
#define GTK 32

__global__ __launch_bounds__(256) void gemm_bf(
    const bf16* __restrict__ A, int lda,
    const bf16* __restrict__ B, int ldb,
    float* __restrict__ C, int ldc,
    int N, int K, int epi,
    const float* __restrict__ bias,
    const float* __restrict__ resid,
    bf16* __restrict__ C2)
{
    __shared__ short As[GTM * GTK];   // 8 KB
    __shared__ short Bs[GTN * GTK];   // 8 KB
    const int tid  = threadIdx.x;
    const int lane = tid & 63;
    const int wave = tid >> 6;            // 0..3
    const int wm = (wave & 1) * 64;
    const int wn = (wave >> 1) * 64;
    const int bm = blockIdx.y * GTM;
    const int bn = blockIdx.x * GTN;
    const int kbase = blockIdx.z * K;     // split-K base (K = slice length)

    floatx4 acc[4][4];
#pragma unroll
    for (int i = 0; i < 4; ++i)
#pragma unroll
        for (int j = 0; j < 4; ++j) acc[i][j] = (floatx4){0.f, 0.f, 0.f, 0.f};

    const int srow = wave * 16 + (lane >> 2);   // 0..63 (per pass)
    const int scol = (lane & 3) * 8;            // bf16 col within k-tile
    const int fm = lane & 15;
    const int q  = lane >> 4;

    for (int k0 = 0; k0 < K; k0 += GTK) {
#pragma unroll
        for (int r = 0; r < 2; ++r) {
            const int m = r * 64 + srow;
            gload16(A + (size_t)(bm + m) * lda + kbase + k0 + scol,
                    As + m * GTK + scol);
            gload16(B + (size_t)(bn + m) * ldb + kbase + k0 + scol,
                    Bs + m * GTK + scol);
        }
        __syncthreads();

        short8 af[4], bfr[4];
#pragma unroll
        for (int i = 0; i < 4; ++i)
            af[i] = *(short8*)&As[(wm + i * 16 + fm) * GTK + q * 8];
#pragma unroll
        for (int j = 0; j < 4; ++j)
            bfr[j] = *(short8*)&Bs[(wn + j * 16 + fm) * GTK + q * 8];
#pragma unroll
        for (int i = 0; i < 4; ++i)
#pragma unroll
            for (int j = 0; j < 4; ++j)
                acc[i][j] = __builtin_amdgcn_mfma_f32_16x16x32_bf16(
                    af[i], bfr[j], acc[i][j], 0, 0, 0);
        __syncthreads();
    }

    const int col = lane & 15;
    const int rq  = (lane >> 4) * 4;
#pragma unroll
    for (int i = 0; i < 4; ++i) {
#pragma unroll
        for (int j = 0; j < 4; ++j) {
#pragma unroll
            for (int r = 0; r < 4; ++r) {
                const int gm = bm + wm + i * 16 + rq + r;
                const int gn = bn + wn + j * 16 + col;
                if (gn >= N) continue;
                float v = acc[i][j][r];
                if (epi == 1) {
                    C[(size_t)gm * ldc + gn] = fsoftp(v + bias[gn]);
                } else if (epi == 2) {
                    C[(size_t)gm * ldc + gn] = v + resid[(size_t)gm * ldc + gn];
                } else if (epi == 3) {
                    atomicAdd(&C[(size_t)gm * ldc + gn], v);
                } else {
                    if (gn < D_INNER) C[(size_t)gm * ldc + gn] = v;
                    else C2[(size_t)gm * (size_t)D_INNER + (gn - D_INNER)] = f2b(v);
                }
            }
        }
    }
}

// ------------- conv(4)+SiLU from contiguous uraw; fp32 + bf16 out -----------
__global__ __launch_bounds__(256) void conv_par3(
    const float* __restrict__ uraw, const float* __restrict__ cw,
    const float* __restrict__ cb, float* __restrict__ uc, bf16* __restrict__ ucb)
{
    const int id = blockIdx.x * 256 + threadIdx.x;  // = (b*LL+t)*D_INNER+d
    const int d = id & (D_INNER - 1);
    const int t = (id >> 11) & (LL - 1);
    float acc = cb[d];
#pragma unroll
    for (int k = 0; k < 4; ++k) {
        const int tt = t - 3 + k;
        if (tt >= 0) acc += uraw[(size_t)id + (size_t)(k - 3) * D_INNER] * cw[d * 4 + k];
    }
    const float s = acc * fsig(acc);
    uc[id] = s;
    ucb[id] = f2b(s);
}

// ------------- dbl[:, :64] -> bf16 dt_r copy for GEMM-5 ----------------------
__global__ __launch_bounds__(256) void cvt_dtr(
    const float* __restrict__ dbl, bf16* __restrict__ dtr_bf)
{
    const int id = blockIdx.x * 256 + threadIdx.x;  // m*64+r
    const int m = id >> 6, r = id & 63;
    dtr_bf[id] = f2b(dbl[(size_t)m * DBL_LD + r]);
}

// ------------------------------ 3-phase scan ---------------------------------
__global__ __launch_bounds__(256) void scan_p1(
    const float* __restrict__ uc, const float* __restrict__ dtb,
    const float* __restrict__ dbl, const float* __restrict__ A_log,
    float* __restrict__ Psum, float* __restrict__ Hloc)
{
    const int blk = blockIdx.x;
    const int d = (blk & 7) * 256 + threadIdx.x;
    const int c = (blk >> 3) & (NCH - 1);
    const int b = blk >> 8;
    float A[D_STATE], h[D_STATE];
#pragma unroll
    for (int n = 0; n < D_STATE; ++n) {
        A[n] = -__expf(A_log[d * D_STATE + n]);
        h[n] = 0.f;
    }
    const size_t row0 = (size_t)b * LL + c * TCH;
    const float* dtp = dtb + row0 * D_INNER + d;
    const float* up  = uc  + row0 * D_INNER + d;
    const float* Bp  = dbl + row0 * DBL_LD + DT_RANK;
    float S = 0.f;
    for (int t = 0; t < TCH; ++t) {
        const float dtv = dtp[(size_t)t * D_INNER];
        const float uv  = up[(size_t)t * D_INNER];
        const float du  = dtv * uv;
        S += dtv;
#pragma unroll
        for (int n = 0; n < D_STATE; ++n)
            h[n] = __expf(dtv * A[n]) * h[n] + du * Bp[(size_t)t * DBL_LD + n];
    }
    const size_t o = (((size_t)b * NCH + c) * D_INNER + d) * D_STATE;
#pragma unroll
    for (int n = 0; n < D_STATE; ++n) {
        Psum[o + n] = __expf(S * A[n]);
        Hloc[o + n] = h[n];
    }
}

__global__ __launch_bounds__(256) void scan_p2(
    float* __restrict__ Psum, const float* __restrict__ Hloc)
{
    const int id = blockIdx.x * 256 + threadIdx.x;
    const int dn = id & (D_INNER * D_STATE - 1);
    const int b  = id >> 15;
    float h = 0.f;
    for (int c = 0; c < NCH; ++c) {
        const size_t o = ((size_t)(b * NCH + c) * D_INNER * D_STATE) + dn;
        const float P  = Psum[o];
        const float hl = Hloc[o];
        Psum[o] = h;          // Hin for chunk c
        h = P * h + hl;
    }
}

__global__ __launch_bounds__(256) void scan_p3b(
    const float* __restrict__ uc, const float* __restrict__ dtb,
    const float* __restrict__ dbl, const float* __restrict__ A_log,
    const float* __restrict__ Dw, const float* __restrict__ Hin,
    const bf16* __restrict__ zbf, bf16* __restrict__ ybf)
{
    const int blk = blockIdx.x;
    const int d = (blk & 7) * 256 + threadIdx.x;
    const int c = (blk >> 3) & (NCH - 1);
    const int b = blk >> 8;
    float A[D_STATE], h[D_STATE];
    const size_t o = (((size_t)b * NCH + c) * D_INNER + d) * D_STATE;
#pragma unroll
    for (int n = 0; n < D_STATE; ++n) {
        A[n] = -__expf(A_log[d * D_STATE + n]);
        h[n] = Hin[o + n];
    }
    const float Dd = Dw[d];
    const size_t row0 = (size_t)b * LL + c * TCH;
    const float* dtp = dtb + row0 * D_INNER + d;
    const float* up  = uc  + row0 * D_INNER + d;
    const float* BCp = dbl + row0 * DBL_LD;
    const bf16* zp   = zbf + row0 * D_INNER + d;
    bf16* yp         = ybf + row0 * D_INNER + d;
    for (int t = 0; t < TCH; ++t) {
        const float dtv = dtp[(size_t)t * D_INNER];
        const float uv  = up[(size_t)t * D_INNER];
        const float du  = dtv * uv;
        float acc = uv * Dd;
        const float* Brow = BCp + (size_t)t * DBL_LD + DT_RANK;
        const float* Crow = Brow + D_STATE;
#pragma unroll
        for (int n = 0; n < D_STATE; ++n) {
            h[n] = __expf(dtv * A[n]) * h[n] + du * Brow[n];
            acc += h[n] * Crow[n];
        }
        const float zv = (float)zp[(size_t)t * D_INNER];
        yp[(size_t)t * D_INNER] = f2b(acc * zv * fsig(zv));
    }
}

// ---------------- fallback (small ws): R4 sequential path --------------------
#define BM 128
#define BN 128
#define BK 8

__global__ __launch_bounds__(256) void gemm_bt(
    const float* __restrict__ A, int lda,
    const float* __restrict__ Bw,
    float* __restrict__ C, int ldc,
    int M, int N, int K, int epi,
    const float* __restrict__ bias,
    const float* __restrict__ resid)
{
    __shared__ float As[BK][BM + 1];
    __shared__ float Bs[BK][BN + 1];
    const int tx = threadIdx.x, ty = threadIdx.y;
    const int tid = ty * 16 + tx;
    const int bm = blockIdx.y * BM, bn = blockIdx.x * BN;
    float acc[8][8];
#pragma unroll
    for (int i = 0; i < 8; ++i)
#pragma unroll
        for (int j = 0; j < 8; ++j) acc[i][j] = 0.f;
    for (int k0 = 0; k0 < K; k0 += BK) {
#pragma unroll
        for (int i = tid; i < BM * BK; i += 256) {
            const int m = i / BK, kk = i % BK;
            As[kk][m] = A[(size_t)(bm + m) * lda + (k0 + kk)];
        }
#pragma unroll
        for (int i = tid; i < BN * BK; i += 256) {
            const int n = i / BK, kk = i % BK;
            const int gn = bn + n;
            Bs[kk][n] = (gn < N) ? Bw[(size_t)gn * K + (k0 + kk)] : 0.f;
        }
        __syncthreads();
#pragma unroll
        for (int kk = 0; kk < BK; ++kk) {
            float av[8], bv[8];
#pragma unroll
            for (int i = 0; i < 8; ++i) av[i] = As[kk][ty * 8 + i];
#pragma unroll
            for (int j = 0; j < 8; ++j) bv[j] = Bs[kk][tx * 8 + j];
#pragma unroll
            for (int i = 0; i < 8; ++i)
#pragma unroll
                for (int j = 0; j < 8; ++j) acc[i][j] += av[i] * bv[j];
        }
        __syncthreads();
    }
#pragma unroll
    for (int i = 0; i < 8; ++i) {
        const int gm = bm + ty * 8 + i;
#pragma unroll
        for (int j = 0; j < 8; ++j) {
            const int gn = bn + tx * 8 + j;
            if (gn >= N) continue;
            float v = acc[i][j];
            if (epi == 1) {
                v += bias[gn];
                v = fmaxf(v, 0.f) + log1pf(expf(-fabsf(v)));
            } else if (epi == 2) {
                v += resid[(size_t)gm * ldc + gn];
            }
            C[(size_t)gm * ldc + gn] = v;
        }
    }
}

__global__ __launch_bounds__(256) void conv_silu_kernel(
    float* __restrict__ xz, const float* __restrict__ cw,
    const float* __restrict__ cb)
{
    const int idx = blockIdx.x * 256 + threadIdx.x;
    const int b = idx >> 11, d = idx & (D_INNER - 1);
    const float w0 = cw[d * 4 + 0], w1 = cw[d * 4 + 1];
    const float w2 = cw[d * 4 + 2], w3 = cw[d * 4 + 3];
    const float bias = cb[d];
    float* u = xz + (size_t)b * LL * XZ_LD + d;
    float x0 = 0.f, x1 = 0.f, x2 = 0.f;
    for (int t = 0; t < LL; ++t) {
        const float x3 = u[(size_t)t * XZ_LD];
        const float c = bias + x0 * w0 + x1 * w1 + x2 * w2 + x3 * w3;
        u[(size_t)t * XZ_LD] = c / (1.f + expf(-c));
        x0 = x1; x1 = x2; x2 = x3;
    }
}

__global__ __launch_bounds__(256) void scan_kernel(
    float* __restrict__ xz, const float* __restrict__ dtb,
    const float* __restrict__ dbl,
    const float* __restrict__ A_log, const float* __restrict__ Dw)
{
    const int idx = blockIdx.x * 256 + threadIdx.x;
    const int b = idx >> 11, d = idx & (D_INNER - 1);
    float A[D_STATE], h[D_STATE];
#pragma unroll
    for (int n = 0; n < D_STATE; ++n) {
        A[n] = -expf(A_log[d * D_STATE + n]);
        h[n] = 0.f;
    }
    const float Dd = Dw[d];
    const float* dtp  = dtb + (size_t)b * LL * D_INNER + d;
    float*       up   = xz  + (size_t)b * LL * XZ_LD + d;
    const float* dblp = dbl + (size_t)b * LL * DBL_LD;
    for (int t = 0; t < LL; ++t) {
        const float dtv = dtp[(size_t)t * D_INNER];
        const float uv  = up[(size_t)t * XZ_LD];
        const float zv  = up[(size_t)t * XZ_LD + D_INNER];
        const float* Brow = dblp + (size_t)t * DBL_LD + DT_RANK;
        const float* Crow = Brow + D_STATE;
        const float du = dtv * uv;
        float acc = uv * Dd;
#pragma unroll
        for (int n = 0; n < D_STATE; ++n) {
            const float dA = expf(dtv * A[n]);
            h[n] = dA * h[n] + du * Brow[n];
            acc += h[n] * Crow[n];
        }
        const float sz = zv / (1.f + expf(-zv));
        up[(size_t)t * XZ_LD] = acc * sz;
    }
}

extern "C" void kernel_launch(void* const* d_in, const int* in_sizes, int n_in,
                              void* d_out, int out_size, void* d_ws, size_t ws_size,
                              hipStream_t stream)
{
    const float* x       = (const float*)d_in[0];
    const float* ln_w    = (const float*)d_in[1];
    const float* ln_b    = (const float*)d_in[2];
    const float* W_in    = (const float*)d_in[3];
    const float* conv_w  = (const float*)d_in[4];
    const float* conv_b  = (const float*)d_in[5];
    const float* W_xproj = (const float*)d_in[6];
    const float* W_dt    = (const float*)d_in[7];
    const float* b_dt    = (const float*)d_in[8];
    const float* A_log   = (const float*)d_in[9];
    const float* Dw      = (const float*)d_in[10];
    const float* W_out   = (const float*)d_in[11];
    float* out = (float*)d_out;

    // big-path ws layout (float offsets from base):
    //   dtb   [0,        8388608)   dt; early alias: xn_bf | win_bf
    //   uraw  [8388608, 16777216)   G2 u-out; later alias: Psum|Hloc|dtr_bf
    //   zbf   [16777216, 20971520)  bf16 z (4194304 f)
    //   dbl   [20971520, 21364736)
    //   uc    [21364736, 29753344)
    //   ucy   [29753344, 33947648)  bf16 uc, then bf16 y
    //   wx_bf [33947648, ..) wdt_bf wout_bf -> end 35192832 f = 134.3 MiB
    float* wsf    = (float*)d_ws;
    float* dtb    = wsf;
    bf16*  xn_bf  = (bf16*)dtb;
    bf16*  win_bf = (bf16*)(dtb + 2097152);
    float* uraw   = wsf + 8388608;
    float* Psum   = uraw;
    float* Hloc   = uraw + 2097152;
    bf16*  dtr_bf = (bf16*)(uraw + 4194304);
    bf16*  zbf    = (bf16*)(wsf + 16777216);
    float* dbl    = wsf + 20971520;
    float* uc     = wsf + 21364736;
    bf16*  ucy    = (bf16*)(wsf + 29753344);
    bf16*  wx_bf  = (bf16*)(wsf + 33947648);
    bf16*  wdt_bf = wx_bf + S1;
    bf16*  wout_bf= wdt_bf + S2;
    const size_t need_big = (size_t)35192832 * sizeof(float);

    if (ws_size >= need_big) {
        wcvt_kernel<<<(S0 + S1 + S2 + S3 + S4) / 256, 256, 0, stream>>>(
            W_in, W_xproj, W_dt, W_out, win_bf, wx_bf, wdt_bf, wout_bf, dbl);
        ln_kernel<<<BL, 256, 0, stream>>>(x, ln_w, ln_b, nullptr, xn_bf);
        // out := x  (residual pre-init; G7 accumulates atomically)
        init_out<<<BL * D_MODEL / 4 / 256, 256, 0, stream>>>(x, out);
        // G2: [u|z] = xn @ W_in^T  (M=4096, N=4096, K=1024)
        gemm_bf<<<dim3(XZ_LD / GTN, BL / GTM, 1), 256, 0, stream>>>(
            xn_bf, D_MODEL, win_bf, D_MODEL, uraw, D_INNER,
            XZ_LD, D_MODEL, 4, nullptr, nullptr, zbf);
        conv_par3<<<(size_t)BL * D_INNER / 256, 256, 0, stream>>>(
            uraw, conv_w, conv_b, uc, ucy);
        // G4: dbl += uc @ W_xproj^T  (N=96 pad 128, split-K=8, atomic)
        gemm_bf<<<dim3(1, BL / GTM, 8), 256, 0, stream>>>(
            ucy, D_INNER, wx_bf, D_INNER, dbl, DBL_LD,
            DBL_LD, D_INNER / 8, 3, nullptr, nullptr, nullptr);
        cvt_dtr<<<BL * DT_RANK / 256, 256, 0, stream>>>(dbl, dtr_bf);
        // G5: dt = softplus(dt_r @ W_dt^T + b_dt)  (N=2048, K=64)
        gemm_bf<<<dim3(D_INNER / GTN, BL / GTM, 1), 256, 0, stream>>>(
            dtr_bf, DT_RANK, wdt_bf, DT_RANK, dtb, D_INNER,
            D_INNER, DT_RANK, 1, b_dt, nullptr, nullptr);
        scan_p1<<<BB * NCH * 8, 256, 0, stream>>>(uc, dtb, dbl, A_log, Psum, Hloc);
        scan_p2<<<BB * D_INNER * D_STATE / 256, 256, 0, stream>>>(Psum, Hloc);
        scan_p3b<<<BB * NCH * 8, 256, 0, stream>>>(
            uc, dtb, dbl, A_log, Dw, Psum, zbf, ucy);
        // G7: out += y @ W_out^T  (N=1024, split-K=4, atomic; out pre-init to x)
        gemm_bf<<<dim3(D_MODEL / GTN, BL / GTM, 4), 256, 0, stream>>>(
            ucy, D_INNER, wout_bf, D_INNER, out, D_MODEL,
            D_MODEL, D_INNER / 4, 3, nullptr, nullptr, nullptr);
    } else {
        float* fdtb = wsf;
        float* fxn  = fdtb;
        float* fxz  = fdtb + (size_t)BL * D_INNER;
        float* fdbl = fxz + (size_t)BL * XZ_LD;
        ln_kernel<<<BL, 256, 0, stream>>>(x, ln_w, ln_b, fxn, nullptr);
        dim3 blk(16, 16);
        gemm_bt<<<dim3(XZ_LD / BN, BL / BM), blk, 0, stream>>>(
            fxn, D_MODEL, W_in, fxz, XZ_LD, BL, XZ_LD, D_MODEL, 0, nullptr, nullptr);
        conv_silu_kernel<<<(BB * D_INNER) / 256, 256, 0, stream>>>(fxz, conv_w, conv_b);
        gemm_bt<<<dim3(1, BL / BM), blk, 0, stream>>>(
            fxz, XZ_LD, W_xproj, fdbl, DBL_LD, BL, DBL_LD, D_INNER, 0, nullptr, nullptr);
        gemm_bt<<<dim3(D_INNER / BN, BL / BM), blk, 0, stream>>>(
            fdbl, DBL_LD, W_dt, fdtb, D_INNER, BL, D_INNER, DT_RANK, 1, b_dt, nullptr);
        scan_kernel<<<(BB * D_INNER) / 256, 256, 0, stream>>>(fxz, fdtb, fdbl, A_log, Dw);
        gemm_bt<<<dim3(D_MODEL / BN, BL / BM), blk, 0, stream>>>(
            fxz, XZ_LD, W_out, out, D_MODEL, BL, D_MODEL, D_INNER, 2, nullptr, x);
    }
}